// Round 2
// baseline (4905.252 us; speedup 1.0000x reference)
//
#include <hip/hip_runtime.h>
#include <hip/hip_bf16.h>

// Problem constants (MultiScaleRetention: B=2, N=4096, D_MODEL=2048, H=4)
constexpr int Bb   = 2;
constexpr int Nn   = 4096;
constexpr int DM   = 2048;
constexpr int Hh   = 4;
constexpr int DK   = 256;    // KEY_DIM / H
constexpr int DV   = 512;    // D_MODEL / H
constexpr int KEYD = 1024;
constexpr int CH   = 64;     // chunk
constexpr int NC   = Nn / CH;   // 64 chunks
constexpr int M    = Bb * Nn;   // 8192 rows

// ---------------------------------------------------------------------------
// Generic fp32 GEMM: C[M,N] = A[M,K] @ W[N,K]^T  (both row-major, K contig)
// 128x128 tile, BK=16, 256 threads, 8x8 microtile. All dims multiples of 128/16.
// ---------------------------------------------------------------------------
__global__ __launch_bounds__(256) void gemm_nt(const float* __restrict__ A,
                                               const float* __restrict__ W,
                                               float* __restrict__ C,
                                               int Mm, int Nd, int K) {
  __shared__ float As[16][132];   // [k][m], pad 132 -> 2-way max on scatter writes
  __shared__ float Ws[16][132];
  const int tid = threadIdx.x;
  const int m0 = blockIdx.x * 128;
  const int n0 = blockIdx.y * 128;
  const int tx = tid & 15;        // col group
  const int ty = tid >> 4;        // row group
  const int lr = tid >> 2;        // loader row 0..63
  const int lc = (tid & 3) * 4;   // loader k offset
  float acc[8][8] = {{0.f}};
  const float* Abase = A + (size_t)(m0 + lr) * K + lc;
  const float* Wbase = W + (size_t)(n0 + lr) * K + lc;
  for (int k0 = 0; k0 < K; k0 += 16) {
    float4 a0 = *(const float4*)(Abase + k0);
    float4 a1 = *(const float4*)(Abase + (size_t)64 * K + k0);
    float4 w0 = *(const float4*)(Wbase + k0);
    float4 w1 = *(const float4*)(Wbase + (size_t)64 * K + k0);
    __syncthreads();
    As[lc+0][lr] = a0.x; As[lc+1][lr] = a0.y; As[lc+2][lr] = a0.z; As[lc+3][lr] = a0.w;
    As[lc+0][lr+64] = a1.x; As[lc+1][lr+64] = a1.y; As[lc+2][lr+64] = a1.z; As[lc+3][lr+64] = a1.w;
    Ws[lc+0][lr] = w0.x; Ws[lc+1][lr] = w0.y; Ws[lc+2][lr] = w0.z; Ws[lc+3][lr] = w0.w;
    Ws[lc+0][lr+64] = w1.x; Ws[lc+1][lr+64] = w1.y; Ws[lc+2][lr+64] = w1.z; Ws[lc+3][lr+64] = w1.w;
    __syncthreads();
#pragma unroll
    for (int kk = 0; kk < 16; ++kk) {
      float4 av0 = *(const float4*)&As[kk][ty*8];
      float4 av1 = *(const float4*)&As[kk][ty*8+4];
      float4 wv0 = *(const float4*)&Ws[kk][tx*8];
      float4 wv1 = *(const float4*)&Ws[kk][tx*8+4];
      float a[8] = {av0.x,av0.y,av0.z,av0.w,av1.x,av1.y,av1.z,av1.w};
      float w[8] = {wv0.x,wv0.y,wv0.z,wv0.w,wv1.x,wv1.y,wv1.z,wv1.w};
#pragma unroll
      for (int ii = 0; ii < 8; ++ii)
#pragma unroll
        for (int jj = 0; jj < 8; ++jj)
          acc[ii][jj] = fmaf(a[ii], w[jj], acc[ii][jj]);
    }
  }
#pragma unroll
  for (int ii = 0; ii < 8; ++ii) {
    float4 s0 = make_float4(acc[ii][0], acc[ii][1], acc[ii][2], acc[ii][3]);
    float4 s1 = make_float4(acc[ii][4], acc[ii][5], acc[ii][6], acc[ii][7]);
    float* crow = C + (size_t)(m0 + ty*8 + ii) * Nd + n0 + tx*8;
    *(float4*)crow = s0;
    *(float4*)(crow + 4) = s1;
  }
}

// ---------------------------------------------------------------------------
// RoPE on q and k in place; also applies q *= dk^-0.5 (= 1/16) so both the
// attn kernel and the scan's q@S phase see the scaled q (matches reference).
// idx -> (b, n, h, i) with i in [0,128) the freq index.
// ---------------------------------------------------------------------------
__global__ void rope_kernel(float* __restrict__ q, float* __restrict__ k) {
  const int idx = blockIdx.x * 256 + threadIdx.x;   // < B*N*H*128 = 4,194,304
  const int i = idx & 127;
  const int h = (idx >> 7) & 3;
  const int n = (idx >> 9) & (Nn - 1);
  const int b = idx >> 21;
  const size_t base = ((size_t)(b * Nn + n)) * KEYD + h * DK;
  // inv_freq = 10000^(-i/128); compute in double, round to fp32 like reference
  const float invf = (float)exp((double)i * -0.071955784156063938);  // ln(1e4)/128
  const float theta = (float)n * invf;
  float sn, cs;
  sincosf(theta, &sn, &cs);
  float x1 = q[base + i], x2 = q[base + 128 + i];
  q[base + i]       = (x1 * cs - x2 * sn) * 0.0625f;
  q[base + 128 + i] = (x2 * cs + x1 * sn) * 0.0625f;
  x1 = k[base + i]; x2 = k[base + 128 + i];
  k[base + i]       = x1 * cs - x2 * sn;
  k[base + 128 + i] = x2 * cs + x1 * sn;
}

// ---------------------------------------------------------------------------
// Intra-chunk attention: attn[b,h,c,i,j] = (q_i . k_j) * gamma^(i-j) [i>=j]
// One block per (b,h,c). LDS d-tiled (64-wide) dot products. q pre-scaled.
// ---------------------------------------------------------------------------
__global__ __launch_bounds__(256) void attn_kernel(const float* __restrict__ q,
                                                   const float* __restrict__ k,
                                                   float* __restrict__ attn) {
  const int c = blockIdx.x & 63;
  const int h = (blockIdx.x >> 6) & 3;
  const int b = blockIdx.x >> 8;
  const int tid = threadIdx.x;
  __shared__ float qs[64][68];
  __shared__ float ks[64][68];
  const int i_  = tid >> 2;        // row 0..63
  const int jb  = tid & 3;         // j = jb + 4*jj  (stride-4 to dodge LDS conflicts)
  const int lr  = tid >> 2;        // loader row
  const int lc0 = (tid & 3) * 16;  // loader col
  float acc[16] = {};
  const float* qsrc = q + ((size_t)(b * Nn + c * CH + lr)) * KEYD + h * DK + lc0;
  const float* ksrc = k + ((size_t)(b * Nn + c * CH + lr)) * KEYD + h * DK + lc0;
  for (int dt = 0; dt < 4; ++dt) {
    __syncthreads();
#pragma unroll
    for (int u = 0; u < 4; ++u) {
      *(float4*)&qs[lr][lc0 + 4*u] = *(const float4*)(qsrc + dt*64 + 4*u);
      *(float4*)&ks[lr][lc0 + 4*u] = *(const float4*)(ksrc + dt*64 + 4*u);
    }
    __syncthreads();
    float4 qr[16];
#pragma unroll
    for (int d4 = 0; d4 < 16; ++d4) qr[d4] = *(const float4*)&qs[i_][d4*4];
#pragma unroll
    for (int jj = 0; jj < 16; ++jj) {
      const int j = jb + jj * 4;
      float s = 0.f;
#pragma unroll
      for (int d4 = 0; d4 < 16; ++d4) {
        float4 kk4 = *(const float4*)&ks[j][d4*4];
        s = fmaf(qr[d4].x, kk4.x, s); s = fmaf(qr[d4].y, kk4.y, s);
        s = fmaf(qr[d4].z, kk4.z, s); s = fmaf(qr[d4].w, kk4.w, s);
      }
      acc[jj] += s;
    }
  }
  const float gamma = 1.f - exp2f(-5.f - (float)h);
  const float l2g = log2f(gamma);
  float* arow = attn + ((((size_t)b * Hh + h) * NC + c) * CH + i_) * CH;
#pragma unroll
  for (int jj = 0; jj < 16; ++jj) {
    const int j = jb + jj * 4;
    arow[j] = (i_ >= j) ? acc[jj] * exp2f((float)(i_ - j) * l2g) : 0.f;
  }
}

// ---------------------------------------------------------------------------
// Sequential chunk scan. Grid = B*H*16 (DV split into 16 slices of 32).
// State slice S[256][32] lives in registers (thread tid owns dk-row tid, 32
// VGPRs), mirrored to LDS each chunk for the o_inter = q@S phase.
//   o[i,v] = sum_j attn[i,j] v[j,v]  +  gamma^(i+1) * sum_d q[i,d] S[d,v]
//   S     = gamma^64 * S + sum_j gamma^(63-j) k[j,:]^T v[j,:]
// ---------------------------------------------------------------------------
__global__ __launch_bounds__(256) void scan_kernel(const float* __restrict__ q,
                                                   const float* __restrict__ k,
                                                   const float* __restrict__ v,
                                                   const float* __restrict__ attn,
                                                   float* __restrict__ o) {
  const int tid = threadIdx.x;
  const int s = blockIdx.x & 15;
  const int h = (blockIdx.x >> 4) & 3;
  const int b = blockIdx.x >> 6;
  const int vg0 = s * 32;
  __shared__ float Sl[256][36];   // pre-update state mirror (36: pad + 16B align)
  __shared__ float vl[64][36];    // v tile slice
  float Sreg[32];
#pragma unroll
  for (int u = 0; u < 32; ++u) Sreg[u] = 0.f;
  const float gamma = 1.f - exp2f(-5.f - (float)h);
  const float l2g = log2f(gamma);
  const float gC = exp2f(64.f * l2g);               // gamma^64
  const int i_ = tid >> 2;                          // output row 0..63
  const int v0 = (tid & 3) * 8;                     // output col offset (8 wide)
  const float g_in = exp2f((float)(i_ + 1) * l2g);  // gamma^(i+1)

  for (int c = 0; c < NC; ++c) {
    const int n0 = c * CH;
    // stage v tile slice (64x32) — thread loads 8 consecutive floats
    {
      const float* src = v + ((size_t)(b * Nn + n0 + i_)) * DM + h * DV + vg0 + v0;
      *(float4*)&vl[i_][v0]     = *(const float4*)src;
      *(float4*)&vl[i_][v0 + 4] = *(const float4*)(src + 4);
    }
    // mirror pre-update S to LDS (row tid)
#pragma unroll
    for (int u = 0; u < 32; u += 4)
      *(float4*)&Sl[tid][u] = make_float4(Sreg[u], Sreg[u+1], Sreg[u+2], Sreg[u+3]);
    __syncthreads();

    // ---- output: o_intra + g_in * o_inter for (row i_, cols v0..v0+7) ----
    float accA[8] = {};
    float accI[8] = {};
    const float* arow = attn + ((((size_t)b * Hh + h) * NC + c) * CH + i_) * CH;
#pragma unroll 4
    for (int j = 0; j < 64; ++j) {
      const float a = arow[j];
      float4 x0 = *(const float4*)&vl[j][v0];
      float4 x1 = *(const float4*)&vl[j][v0 + 4];
      accA[0] = fmaf(a, x0.x, accA[0]); accA[1] = fmaf(a, x0.y, accA[1]);
      accA[2] = fmaf(a, x0.z, accA[2]); accA[3] = fmaf(a, x0.w, accA[3]);
      accA[4] = fmaf(a, x1.x, accA[4]); accA[5] = fmaf(a, x1.y, accA[5]);
      accA[6] = fmaf(a, x1.z, accA[6]); accA[7] = fmaf(a, x1.w, accA[7]);
    }
    const float* qrow = q + ((size_t)(b * Nn + n0 + i_)) * KEYD + h * DK;
#pragma unroll 4
    for (int d = 0; d < 256; ++d) {
      const float qv = qrow[d];
      float4 s0 = *(const float4*)&Sl[d][v0];
      float4 s1 = *(const float4*)&Sl[d][v0 + 4];
      accI[0] = fmaf(qv, s0.x, accI[0]); accI[1] = fmaf(qv, s0.y, accI[1]);
      accI[2] = fmaf(qv, s0.z, accI[2]); accI[3] = fmaf(qv, s0.w, accI[3]);
      accI[4] = fmaf(qv, s1.x, accI[4]); accI[5] = fmaf(qv, s1.y, accI[5]);
      accI[6] = fmaf(qv, s1.z, accI[6]); accI[7] = fmaf(qv, s1.w, accI[7]);
    }
    float* orow = o + ((size_t)(b * Nn + n0 + i_)) * DM + h * DV + vg0 + v0;
    *(float4*)orow = make_float4(accA[0] + g_in*accI[0], accA[1] + g_in*accI[1],
                                 accA[2] + g_in*accI[2], accA[3] + g_in*accI[3]);
    *(float4*)(orow + 4) = make_float4(accA[4] + g_in*accI[4], accA[5] + g_in*accI[5],
                                       accA[6] + g_in*accI[6], accA[7] + g_in*accI[7]);

    // ---- state update: Sreg = gC*Sreg + sum_j gamma^(63-j) k[j][tid] v[j][:] ----
#pragma unroll
    for (int u = 0; u < 32; ++u) Sreg[u] *= gC;
    const float* kcol = k + ((size_t)(b * Nn + n0)) * KEYD + h * DK + tid;
#pragma unroll 2
    for (int j = 0; j < 64; ++j) {
      const float kd = kcol[(size_t)j * KEYD] * exp2f((float)(63 - j) * l2g);
#pragma unroll
      for (int u = 0; u < 32; u += 4) {
        float4 x = *(const float4*)&vl[j][u];   // broadcast (same addr all lanes)
        Sreg[u]   = fmaf(kd, x.x, Sreg[u]);
        Sreg[u+1] = fmaf(kd, x.y, Sreg[u+1]);
        Sreg[u+2] = fmaf(kd, x.z, Sreg[u+2]);
        Sreg[u+3] = fmaf(kd, x.w, Sreg[u+3]);
      }
    }
    __syncthreads();   // protect vl/Sl before next chunk's staging
  }
}

// ---------------------------------------------------------------------------
// GroupNorm over DV per (b,n,h) + SiLU gate, in place into g:
//   g[b,n,:] = o_n * rsqrt(mean(o^2)+eps) * gnorm_w * silu(g)
// One block per (b,n); wave w (64 lanes) handles h-group w (512 elems, 8/lane).
// ---------------------------------------------------------------------------
__global__ __launch_bounds__(256) void gn_gate(const float* __restrict__ o,
                                               float* __restrict__ g,
                                               const float* __restrict__ gw) {
  const int bn = blockIdx.x;
  const int tid = threadIdx.x;
  const int h = tid >> 6;
  const int lane = tid & 63;
  const size_t base = (size_t)bn * DM + h * DV + lane * 8;
  float4 o0 = *(const float4*)&o[base];
  float4 o1 = *(const float4*)&o[base + 4];
  float ss = o0.x*o0.x + o0.y*o0.y + o0.z*o0.z + o0.w*o0.w
           + o1.x*o1.x + o1.y*o1.y + o1.z*o1.z + o1.w*o1.w;
#pragma unroll
  for (int m = 1; m < 64; m <<= 1) ss += __shfl_xor(ss, m, 64);
  const float r = rsqrtf(ss * (1.f / 512.f) + 1e-5f);
  float4 g0 = *(const float4*)&g[base];
  float4 g1 = *(const float4*)&g[base + 4];
  const float* gwp = gw + lane * 8;
  float4 r0, r1;
  r0.x = o0.x * r * gwp[0] * (g0.x / (1.f + expf(-g0.x)));
  r0.y = o0.y * r * gwp[1] * (g0.y / (1.f + expf(-g0.y)));
  r0.z = o0.z * r * gwp[2] * (g0.z / (1.f + expf(-g0.z)));
  r0.w = o0.w * r * gwp[3] * (g0.w / (1.f + expf(-g0.w)));
  r1.x = o1.x * r * gwp[4] * (g1.x / (1.f + expf(-g1.x)));
  r1.y = o1.y * r * gwp[5] * (g1.y / (1.f + expf(-g1.y)));
  r1.z = o1.z * r * gwp[6] * (g1.z / (1.f + expf(-g1.z)));
  r1.w = o1.w * r * gwp[7] * (g1.w / (1.f + expf(-g1.w)));
  *(float4*)&g[base]     = r0;
  *(float4*)&g[base + 4] = r1;
}

// ---------------------------------------------------------------------------
// Workspace budget (floats), peak 34M floats = 136 MB (round-0 layout was
// 264 MB and aborted with a GPU memory fault — suspected d_ws overrun):
//   [0 , 8M)   q          (32 MB)   } after scan this 64 MB region is dead
//   [8M, 16M)  k          (32 MB)   } and is reused for g
//   [16M,32M)  v          (64 MB)
//   [32M,34M)  attn       ( 8 MB)
// o (64 MB) lives in d_out until gn_gate consumes it; final GEMM overwrites
// d_out. Every buffer read is fully written earlier in the same launch, so
// graph replays are deterministic.
// ---------------------------------------------------------------------------
extern "C" void kernel_launch(void* const* d_in, const int* in_sizes, int n_in,
                              void* d_out, int out_size, void* d_ws, size_t ws_size,
                              hipStream_t stream) {
  const float* x  = (const float*)d_in[0];
  const float* Wq = (const float*)d_in[1];
  const float* Wk = (const float*)d_in[2];
  const float* Wv = (const float*)d_in[3];
  const float* Wg = (const float*)d_in[4];
  const float* Wo = (const float*)d_in[5];
  const float* gw = (const float*)d_in[6];
  float* out = (float*)d_out;

  float* ws   = (float*)d_ws;
  float* q    = ws;                        // 8M floats
  float* k    = q + (size_t)M * KEYD;      // 8M floats
  float* v    = k + (size_t)M * KEYD;      // 16M floats
  float* attn = v + (size_t)M * DM;        // 2M floats
  float* g    = ws;                        // overlays q+k AFTER scan (16M floats)
  float* o    = (float*)d_out;             // scratch until gn_gate

  dim3 blk(256);
  gemm_nt<<<dim3(M/128, KEYD/128), blk, 0, stream>>>(x, Wq, q, M, KEYD, DM);
  gemm_nt<<<dim3(M/128, KEYD/128), blk, 0, stream>>>(x, Wk, k, M, KEYD, DM);
  gemm_nt<<<dim3(M/128, DM/128),   blk, 0, stream>>>(x, Wv, v, M, DM, DM);
  rope_kernel<<<dim3((Bb*Nn*Hh*128)/256), blk, 0, stream>>>(q, k);
  attn_kernel<<<dim3(Bb*Hh*NC), blk, 0, stream>>>(q, k, attn);
  scan_kernel<<<dim3(Bb*Hh*16), blk, 0, stream>>>(q, k, v, attn, o);
  // q,k dead from here; g overlays them
  gemm_nt<<<dim3(M/128, DM/128),   blk, 0, stream>>>(x, Wg, g, M, DM, DM);
  gn_gate<<<dim3(M), blk, 0, stream>>>(o, g, gw);
  gemm_nt<<<dim3(M/128, DM/128),   blk, 0, stream>>>(g, Wo, out, M, DM, DM);
}

// Round 3
// 1290.424 us; speedup vs baseline: 3.8013x; 3.8013x over previous
//
#include <hip/hip_runtime.h>
#include <hip/hip_bf16.h>
#include <stdint.h>

// Problem constants (MultiScaleRetention: B=2, N=4096, D_MODEL=2048, H=4)
constexpr int Bb   = 2;
constexpr int Nn   = 4096;
constexpr int DM   = 2048;
constexpr int Hh   = 4;
constexpr int DK   = 256;    // KEY_DIM / H
constexpr int DV   = 512;    // D_MODEL / H
constexpr int KEYD = 1024;
constexpr int CH   = 64;     // chunk
constexpr int NC   = Nn / CH;   // 64 chunks
constexpr int M    = Bb * Nn;   // 8192 rows

typedef __attribute__((ext_vector_type(8))) short s16x8;   // 8 bf16 (4 VGPRs)
typedef __attribute__((ext_vector_type(4))) float f32x4;

__device__ __forceinline__ float b2f(uint16_t h) {
  return __uint_as_float(((uint32_t)h) << 16);
}
__device__ __forceinline__ uint16_t f2b(float f) {   // RNE, finite inputs
  uint32_t u = __float_as_uint(f);
  return (uint16_t)((u + 0x7fffu + ((u >> 16) & 1u)) >> 16);
}

// ---------------------------------------------------------------------------
// fp32 -> bf16 bulk convert, 8 elems/thread
// ---------------------------------------------------------------------------
__global__ __launch_bounds__(256) void conv_f2b(const float* __restrict__ s,
                                                uint16_t* __restrict__ d, int n8) {
  int i = blockIdx.x * 256 + threadIdx.x;
  if (i >= n8) return;
  const float4* sp = (const float4*)s;
  float4 a = sp[2 * i], b = sp[2 * i + 1];
  uint4 o;
  o.x = (uint32_t)f2b(a.x) | ((uint32_t)f2b(a.y) << 16);
  o.y = (uint32_t)f2b(a.z) | ((uint32_t)f2b(a.w) << 16);
  o.z = (uint32_t)f2b(b.x) | ((uint32_t)f2b(b.y) << 16);
  o.w = (uint32_t)f2b(b.z) | ((uint32_t)f2b(b.w) << 16);
  ((uint4*)d)[i] = o;
}

// ---------------------------------------------------------------------------
// bf16 MFMA GEMM: C[M,N] = A[M,K] @ W[N,K]^T, A/W bf16 row-major.
// BM=BN=128, BK=32, 256 thr = 4 waves (2x2), wave tile 64x64 = 4x4 frags of
// 16x16x32. LDS rows padded to 40 bf16 (80B: 16B-aligned, 2-way banks).
// A-frag lane l: row=l&15, k=(l>>4)*8+[0..7]; B-frag same on W rows (=cols of B).
// C/D: col=lane&15, row=(lane>>4)*4+reg  (m89/m91-verified).
// ---------------------------------------------------------------------------
template<bool OBF>
__global__ __launch_bounds__(256) void gemm_bf16(const uint16_t* __restrict__ A,
                                                 const uint16_t* __restrict__ W,
                                                 void* __restrict__ Cout,
                                                 int Nd, int K) {
  __shared__ uint16_t As[128 * 40];
  __shared__ uint16_t Bs[128 * 40];
  const int tid = threadIdx.x;
  const int m0 = blockIdx.x * 128, n0 = blockIdx.y * 128;
  const int l = tid & 63, w = tid >> 6;
  const int wr = (w >> 1) * 64, wc = (w & 1) * 64;
  const int fr = l & 15, fk = (l >> 4) * 8;
  const int srow = tid >> 2, sk = (tid & 3) * 8;
  f32x4 acc[4][4];
#pragma unroll
  for (int mi = 0; mi < 4; ++mi)
#pragma unroll
    for (int nj = 0; nj < 4; ++nj) {
      f32x4 z = {0.f, 0.f, 0.f, 0.f};
      acc[mi][nj] = z;
    }
  const uint16_t* Ap = A + (size_t)(m0 + srow) * K + sk;
  const uint16_t* Wp = W + (size_t)(n0 + srow) * K + sk;
  for (int k0 = 0; k0 < K; k0 += 32) {
    s16x8 a0 = *(const s16x8*)(Ap + k0);
    s16x8 a1 = *(const s16x8*)(Ap + (size_t)64 * K + k0);
    s16x8 b0 = *(const s16x8*)(Wp + k0);
    s16x8 b1 = *(const s16x8*)(Wp + (size_t)64 * K + k0);
    __syncthreads();
    *(s16x8*)&As[srow * 40 + sk]        = a0;
    *(s16x8*)&As[(srow + 64) * 40 + sk] = a1;
    *(s16x8*)&Bs[srow * 40 + sk]        = b0;
    *(s16x8*)&Bs[(srow + 64) * 40 + sk] = b1;
    __syncthreads();
    s16x8 af[4], bfr[4];
#pragma unroll
    for (int mi = 0; mi < 4; ++mi)
      af[mi] = *(const s16x8*)&As[(wr + mi * 16 + fr) * 40 + fk];
#pragma unroll
    for (int nj = 0; nj < 4; ++nj)
      bfr[nj] = *(const s16x8*)&Bs[(wc + nj * 16 + fr) * 40 + fk];
#pragma unroll
    for (int mi = 0; mi < 4; ++mi)
#pragma unroll
      for (int nj = 0; nj < 4; ++nj)
        acc[mi][nj] = __builtin_amdgcn_mfma_f32_16x16x32_bf16(af[mi], bfr[nj],
                                                              acc[mi][nj], 0, 0, 0);
  }
  const int r0 = m0 + wr + (l >> 4) * 4;
  const int c0 = n0 + wc + fr;
#pragma unroll
  for (int mi = 0; mi < 4; ++mi)
#pragma unroll
    for (int nj = 0; nj < 4; ++nj)
#pragma unroll
      for (int p = 0; p < 4; ++p) {
        const int row = r0 + mi * 16 + p;
        const int col = c0 + nj * 16;
        const float val = acc[mi][nj][p];
        if (OBF) ((uint16_t*)Cout)[(size_t)row * Nd + col] = f2b(val);
        else     ((float*)Cout)[(size_t)row * Nd + col]    = val;
      }
}

// ---------------------------------------------------------------------------
// RoPE on bf16 q,k in place; q additionally scaled by dk^-0.5 = 1/16.
// ---------------------------------------------------------------------------
__global__ void rope_kernel(uint16_t* __restrict__ q, uint16_t* __restrict__ k) {
  const int idx = blockIdx.x * 256 + threadIdx.x;   // < B*N*H*128
  const int i = idx & 127;
  const int h = (idx >> 7) & 3;
  const int n = (idx >> 9) & (Nn - 1);
  const int b = idx >> 21;
  const size_t base = ((size_t)(b * Nn + n)) * KEYD + h * DK;
  const float invf = (float)exp((double)i * -0.071955784156063938);  // 1e4^(-i/128)
  const float theta = (float)n * invf;
  float sn, cs;
  sincosf(theta, &sn, &cs);
  float x1 = b2f(q[base + i]), x2 = b2f(q[base + 128 + i]);
  q[base + i]       = f2b((x1 * cs - x2 * sn) * 0.0625f);
  q[base + 128 + i] = f2b((x2 * cs + x1 * sn) * 0.0625f);
  x1 = b2f(k[base + i]); x2 = b2f(k[base + 128 + i]);
  k[base + i]       = f2b(x1 * cs - x2 * sn);
  k[base + 128 + i] = f2b(x2 * cs + x1 * sn);
}

// ---------------------------------------------------------------------------
// Intra-chunk attention: attn[b,h,c,i,j] = (q_i . k_j) * gamma^(i-j) [i>=j]
// One block per (b,h,c). bf16 q,k staged to fp32 LDS.
// ---------------------------------------------------------------------------
__global__ __launch_bounds__(256) void attn_kernel(const uint16_t* __restrict__ q,
                                                   const uint16_t* __restrict__ k,
                                                   float* __restrict__ attn) {
  const int c = blockIdx.x & 63;
  const int h = (blockIdx.x >> 6) & 3;
  const int b = blockIdx.x >> 8;
  const int tid = threadIdx.x;
  __shared__ float qs[64][68];
  __shared__ float ks[64][68];
  const int i_  = tid >> 2;
  const int jb  = tid & 3;
  const int lr  = tid >> 2;
  const int lc0 = (tid & 3) * 16;
  float acc[16] = {};
  const uint16_t* qsrc = q + ((size_t)(b * Nn + c * CH + lr)) * KEYD + h * DK + lc0;
  const uint16_t* ksrc = k + ((size_t)(b * Nn + c * CH + lr)) * KEYD + h * DK + lc0;
  for (int dt = 0; dt < 4; ++dt) {
    __syncthreads();
#pragma unroll
    for (int u = 0; u < 2; ++u) {
      uint4 tq = *(const uint4*)(qsrc + dt * 64 + u * 8);
      uint4 tk = *(const uint4*)(ksrc + dt * 64 + u * 8);
      const int cbase = lc0 + u * 8;
      qs[lr][cbase+0] = b2f((uint16_t)tq.x); qs[lr][cbase+1] = b2f((uint16_t)(tq.x>>16));
      qs[lr][cbase+2] = b2f((uint16_t)tq.y); qs[lr][cbase+3] = b2f((uint16_t)(tq.y>>16));
      qs[lr][cbase+4] = b2f((uint16_t)tq.z); qs[lr][cbase+5] = b2f((uint16_t)(tq.z>>16));
      qs[lr][cbase+6] = b2f((uint16_t)tq.w); qs[lr][cbase+7] = b2f((uint16_t)(tq.w>>16));
      ks[lr][cbase+0] = b2f((uint16_t)tk.x); ks[lr][cbase+1] = b2f((uint16_t)(tk.x>>16));
      ks[lr][cbase+2] = b2f((uint16_t)tk.y); ks[lr][cbase+3] = b2f((uint16_t)(tk.y>>16));
      ks[lr][cbase+4] = b2f((uint16_t)tk.z); ks[lr][cbase+5] = b2f((uint16_t)(tk.z>>16));
      ks[lr][cbase+6] = b2f((uint16_t)tk.w); ks[lr][cbase+7] = b2f((uint16_t)(tk.w>>16));
    }
    __syncthreads();
    float4 qr[16];
#pragma unroll
    for (int d4 = 0; d4 < 16; ++d4) qr[d4] = *(const float4*)&qs[i_][d4 * 4];
#pragma unroll
    for (int jj = 0; jj < 16; ++jj) {
      const int j = jb + jj * 4;
      float s = 0.f;
#pragma unroll
      for (int d4 = 0; d4 < 16; ++d4) {
        float4 kk4 = *(const float4*)&ks[j][d4 * 4];
        s = fmaf(qr[d4].x, kk4.x, s); s = fmaf(qr[d4].y, kk4.y, s);
        s = fmaf(qr[d4].z, kk4.z, s); s = fmaf(qr[d4].w, kk4.w, s);
      }
      acc[jj] += s;
    }
  }
  const float gamma = 1.f - exp2f(-5.f - (float)h);
  const float l2g = log2f(gamma);
  float* arow = attn + ((((size_t)b * Hh + h) * NC + c) * CH + i_) * CH;
#pragma unroll
  for (int jj = 0; jj < 16; ++jj) {
    const int j = jb + jj * 4;
    arow[j] = (i_ >= j) ? acc[jj] * exp2f((float)(i_ - j) * l2g) : 0.f;
  }
}

// ---------------------------------------------------------------------------
// Sequential chunk scan. Grid = B*H*64 (DV split into 64 slices of 8) -> 512
// blocks, 2/CU, 8 waves/CU (round-2: was 128 blocks / 6% occupancy).
// Thread tid owns dk-row tid of the state slice S[256][8] (Sreg[8], fp32);
// mirrored to LDS each chunk for the o_inter = q@S phase.
// ---------------------------------------------------------------------------
__global__ __launch_bounds__(256) void scan_kernel(const uint16_t* __restrict__ q,
                                                   const uint16_t* __restrict__ k,
                                                   const uint16_t* __restrict__ v,
                                                   const float* __restrict__ attn,
                                                   float* __restrict__ o) {
  const int tid = threadIdx.x;
  const int s = blockIdx.x & 63;
  const int h = (blockIdx.x >> 6) & 3;
  const int b = blockIdx.x >> 8;
  const int vg0 = s * 8;
  __shared__ float Sl[256][12];   // 48B rows: 16B-aligned float4s, period-8 banks
  __shared__ float vl[64][12];
  float Sreg[8];
#pragma unroll
  for (int u = 0; u < 8; ++u) Sreg[u] = 0.f;
  const float gamma = 1.f - exp2f(-5.f - (float)h);
  const float l2g = log2f(gamma);
  const float gC = exp2f(64.f * l2g);
  const int i_ = tid >> 2;
  const int v0 = (tid & 3) * 2;
  const float g_in = exp2f((float)(i_ + 1) * l2g);

  for (int c = 0; c < NC; ++c) {
    const int n0 = c * CH;
    {
      const uint16_t* src = v + ((size_t)(b * Nn + n0 + i_)) * DM + h * DV + vg0 + v0;
      uint32_t pr = *(const uint32_t*)src;
      vl[i_][v0]     = b2f((uint16_t)pr);
      vl[i_][v0 + 1] = b2f((uint16_t)(pr >> 16));
    }
    *(float4*)&Sl[tid][0] = make_float4(Sreg[0], Sreg[1], Sreg[2], Sreg[3]);
    *(float4*)&Sl[tid][4] = make_float4(Sreg[4], Sreg[5], Sreg[6], Sreg[7]);
    __syncthreads();

    float aA0 = 0.f, aA1 = 0.f, aI0 = 0.f, aI1 = 0.f;
    const float* arow = attn + ((((size_t)b * Hh + h) * NC + c) * CH + i_) * CH;
#pragma unroll 8
    for (int j = 0; j < 64; ++j) {
      const float a = arow[j];
      float2 x = *(const float2*)&vl[j][v0];
      aA0 = fmaf(a, x.x, aA0); aA1 = fmaf(a, x.y, aA1);
    }
    const uint16_t* qrow = q + ((size_t)(b * Nn + n0 + i_)) * KEYD + h * DK;
#pragma unroll 4
    for (int d8 = 0; d8 < 32; ++d8) {
      uint4 t = *(const uint4*)(qrow + d8 * 8);
      const int d = d8 * 8;
      float qv;
      float2 sx;
      qv = b2f((uint16_t)t.x);        sx = *(const float2*)&Sl[d+0][v0]; aI0 = fmaf(qv, sx.x, aI0); aI1 = fmaf(qv, sx.y, aI1);
      qv = b2f((uint16_t)(t.x>>16));  sx = *(const float2*)&Sl[d+1][v0]; aI0 = fmaf(qv, sx.x, aI0); aI1 = fmaf(qv, sx.y, aI1);
      qv = b2f((uint16_t)t.y);        sx = *(const float2*)&Sl[d+2][v0]; aI0 = fmaf(qv, sx.x, aI0); aI1 = fmaf(qv, sx.y, aI1);
      qv = b2f((uint16_t)(t.y>>16));  sx = *(const float2*)&Sl[d+3][v0]; aI0 = fmaf(qv, sx.x, aI0); aI1 = fmaf(qv, sx.y, aI1);
      qv = b2f((uint16_t)t.z);        sx = *(const float2*)&Sl[d+4][v0]; aI0 = fmaf(qv, sx.x, aI0); aI1 = fmaf(qv, sx.y, aI1);
      qv = b2f((uint16_t)(t.z>>16));  sx = *(const float2*)&Sl[d+5][v0]; aI0 = fmaf(qv, sx.x, aI0); aI1 = fmaf(qv, sx.y, aI1);
      qv = b2f((uint16_t)t.w);        sx = *(const float2*)&Sl[d+6][v0]; aI0 = fmaf(qv, sx.x, aI0); aI1 = fmaf(qv, sx.y, aI1);
      qv = b2f((uint16_t)(t.w>>16));  sx = *(const float2*)&Sl[d+7][v0]; aI0 = fmaf(qv, sx.x, aI0); aI1 = fmaf(qv, sx.y, aI1);
    }
    float* orow = o + ((size_t)(b * Nn + n0 + i_)) * DM + h * DV + vg0 + v0;
    float2 r;
    r.x = aA0 + g_in * aI0;
    r.y = aA1 + g_in * aI1;
    *(float2*)orow = r;

#pragma unroll
    for (int u = 0; u < 8; ++u) Sreg[u] *= gC;
    const uint16_t* kcol = k + ((size_t)(b * Nn + n0)) * KEYD + h * DK + tid;
#pragma unroll 4
    for (int j = 0; j < 64; ++j) {
      const float kd = b2f(kcol[(size_t)j * KEYD]) * exp2f((float)(63 - j) * l2g);
      float4 x0 = *(const float4*)&vl[j][0];
      float4 x1 = *(const float4*)&vl[j][4];
      Sreg[0] = fmaf(kd, x0.x, Sreg[0]); Sreg[1] = fmaf(kd, x0.y, Sreg[1]);
      Sreg[2] = fmaf(kd, x0.z, Sreg[2]); Sreg[3] = fmaf(kd, x0.w, Sreg[3]);
      Sreg[4] = fmaf(kd, x1.x, Sreg[4]); Sreg[5] = fmaf(kd, x1.y, Sreg[5]);
      Sreg[6] = fmaf(kd, x1.z, Sreg[6]); Sreg[7] = fmaf(kd, x1.w, Sreg[7]);
    }
    __syncthreads();
  }
}

// ---------------------------------------------------------------------------
// GroupNorm over DV per (b,n,h) + SiLU gate, in place into bf16 g.
// ---------------------------------------------------------------------------
__global__ __launch_bounds__(256) void gn_gate(const float* __restrict__ o,
                                               uint16_t* __restrict__ g,
                                               const float* __restrict__ gw) {
  const int bn = blockIdx.x;
  const int tid = threadIdx.x;
  const int h = tid >> 6;
  const int lane = tid & 63;
  const size_t base = (size_t)bn * DM + h * DV + lane * 8;
  float4 o0 = *(const float4*)&o[base];
  float4 o1 = *(const float4*)&o[base + 4];
  float ss = o0.x*o0.x + o0.y*o0.y + o0.z*o0.z + o0.w*o0.w
           + o1.x*o1.x + o1.y*o1.y + o1.z*o1.z + o1.w*o1.w;
#pragma unroll
  for (int m = 1; m < 64; m <<= 1) ss += __shfl_xor(ss, m, 64);
  const float r = rsqrtf(ss * (1.f / 512.f) + 1e-5f);
  uint4 gv = *(const uint4*)&g[base];
  float gf[8] = { b2f((uint16_t)gv.x), b2f((uint16_t)(gv.x >> 16)),
                  b2f((uint16_t)gv.y), b2f((uint16_t)(gv.y >> 16)),
                  b2f((uint16_t)gv.z), b2f((uint16_t)(gv.z >> 16)),
                  b2f((uint16_t)gv.w), b2f((uint16_t)(gv.w >> 16)) };
  float ov[8] = { o0.x, o0.y, o0.z, o0.w, o1.x, o1.y, o1.z, o1.w };
  const float* gwp = gw + lane * 8;
  uint16_t res[8];
#pragma unroll
  for (int e = 0; e < 8; ++e) {
    float sil = gf[e] / (1.f + expf(-gf[e]));
    res[e] = f2b(ov[e] * r * gwp[e] * sil);
  }
  uint4 outv;
  outv.x = (uint32_t)res[0] | ((uint32_t)res[1] << 16);
  outv.y = (uint32_t)res[2] | ((uint32_t)res[3] << 16);
  outv.z = (uint32_t)res[4] | ((uint32_t)res[5] << 16);
  outv.w = (uint32_t)res[6] | ((uint32_t)res[7] << 16);
  *(uint4*)&g[base] = outv;
}

// ---------------------------------------------------------------------------
// ws layout (bytes), peak 160 MB (known-good 136, known-bad 264):
//   [  0, 32M)  xb  (bf16 x)        -- dead after gb GEMM; attn overlays [0,8M)
//   [ 32, 48M)  qb   [ 48, 64M) kb   [ 64, 96M) vb   [ 96,128M) gb
//   [128,132M)  Wqb  [132,136M) Wkb  [136,144M) Wvb  [144,152M) Wgb [152,160M) Wob
// o (fp32) lives in d_out until gn_gate; final GEMM overwrites d_out.
// All buffers fully written before read within each launch -> graph-replay safe.
// ---------------------------------------------------------------------------
extern "C" void kernel_launch(void* const* d_in, const int* in_sizes, int n_in,
                              void* d_out, int out_size, void* d_ws, size_t ws_size,
                              hipStream_t stream) {
  const float* x  = (const float*)d_in[0];
  const float* Wq = (const float*)d_in[1];
  const float* Wk = (const float*)d_in[2];
  const float* Wv = (const float*)d_in[3];
  const float* Wg = (const float*)d_in[4];
  const float* Wo = (const float*)d_in[5];
  const float* gw = (const float*)d_in[6];

  char* base = (char*)d_ws;
  uint16_t* xb  = (uint16_t*)(base);
  uint16_t* qb  = (uint16_t*)(base + ((size_t)32 << 20));
  uint16_t* kb  = (uint16_t*)(base + ((size_t)48 << 20));
  uint16_t* vb  = (uint16_t*)(base + ((size_t)64 << 20));
  uint16_t* gb  = (uint16_t*)(base + ((size_t)96 << 20));
  uint16_t* wqb = (uint16_t*)(base + ((size_t)128 << 20));
  uint16_t* wkb = (uint16_t*)(base + ((size_t)132 << 20));
  uint16_t* wvb = (uint16_t*)(base + ((size_t)136 << 20));
  uint16_t* wgb = (uint16_t*)(base + ((size_t)144 << 20));
  uint16_t* wob = (uint16_t*)(base + ((size_t)152 << 20));
  float*    attn = (float*)(base);            // overlays xb after it's dead
  float*    o    = (float*)d_out;             // scratch until gn_gate

  dim3 blk(256);
  // fp32 -> bf16 conversions
  conv_f2b<<<dim3(8192), blk, 0, stream>>>(x,  xb,  M * DM / 8);
  conv_f2b<<<dim3(1024), blk, 0, stream>>>(Wq, wqb, KEYD * DM / 8);
  conv_f2b<<<dim3(1024), blk, 0, stream>>>(Wk, wkb, KEYD * DM / 8);
  conv_f2b<<<dim3(2048), blk, 0, stream>>>(Wv, wvb, DM * DM / 8);
  conv_f2b<<<dim3(2048), blk, 0, stream>>>(Wg, wgb, DM * DM / 8);
  conv_f2b<<<dim3(2048), blk, 0, stream>>>(Wo, wob, DM * DM / 8);
  // projections (bf16 MFMA)
  gemm_bf16<true><<<dim3(M/128, KEYD/128), blk, 0, stream>>>(xb, wqb, qb, KEYD, DM);
  gemm_bf16<true><<<dim3(M/128, KEYD/128), blk, 0, stream>>>(xb, wkb, kb, KEYD, DM);
  gemm_bf16<true><<<dim3(M/128, DM/128),   blk, 0, stream>>>(xb, wvb, vb, DM, DM);
  gemm_bf16<true><<<dim3(M/128, DM/128),   blk, 0, stream>>>(xb, wgb, gb, DM, DM);
  // xb dead from here; attn overlays it
  rope_kernel<<<dim3((Bb*Nn*Hh*128)/256), blk, 0, stream>>>(qb, kb);
  attn_kernel<<<dim3(Bb*Hh*NC), blk, 0, stream>>>(qb, kb, attn);
  scan_kernel<<<dim3(Bb*Hh*64), blk, 0, stream>>>(qb, kb, vb, attn, o);
  gn_gate<<<dim3(M), blk, 0, stream>>>(o, gb, gw);
  gemm_bf16<false><<<dim3(M/128, DM/128),  blk, 0, stream>>>(gb, wob, (float*)d_out, DM, DM);
}

// Round 4
// 744.171 us; speedup vs baseline: 6.5916x; 1.7340x over previous
//
#include <hip/hip_runtime.h>
#include <hip/hip_bf16.h>
#include <stdint.h>

// Problem constants (MultiScaleRetention: B=2, N=4096, D_MODEL=2048, H=4)
constexpr int Bb   = 2;
constexpr int Nn   = 4096;
constexpr int DM   = 2048;
constexpr int Hh   = 4;
constexpr int DK   = 256;    // KEY_DIM / H
constexpr int DV   = 512;    // D_MODEL / H
constexpr int KEYD = 1024;
constexpr int CH   = 64;     // chunk
constexpr int NC   = Nn / CH;   // 64 chunks
constexpr int M    = Bb * Nn;   // 8192 rows

typedef __attribute__((ext_vector_type(8))) short s16x8;   // 8 bf16 (4 VGPRs)
typedef __attribute__((ext_vector_type(4))) float f32x4;

__device__ __forceinline__ float b2f(uint16_t h) {
  return __uint_as_float(((uint32_t)h) << 16);
}
__device__ __forceinline__ uint16_t f2b(float f) {   // RNE, finite inputs
  uint32_t u = __float_as_uint(f);
  return (uint16_t)((u + 0x7fffu + ((u >> 16) & 1u)) >> 16);
}

// ---------------------------------------------------------------------------
// fp32 -> bf16 bulk convert, 8 elems/thread
// ---------------------------------------------------------------------------
__global__ __launch_bounds__(256) void conv_f2b(const float* __restrict__ s,
                                                uint16_t* __restrict__ d, int n8) {
  int i = blockIdx.x * 256 + threadIdx.x;
  if (i >= n8) return;
  const float4* sp = (const float4*)s;
  float4 a = sp[2 * i], b = sp[2 * i + 1];
  uint4 o;
  o.x = (uint32_t)f2b(a.x) | ((uint32_t)f2b(a.y) << 16);
  o.y = (uint32_t)f2b(a.z) | ((uint32_t)f2b(a.w) << 16);
  o.z = (uint32_t)f2b(b.x) | ((uint32_t)f2b(b.y) << 16);
  o.w = (uint32_t)f2b(b.z) | ((uint32_t)f2b(b.w) << 16);
  ((uint4*)d)[i] = o;
}

// ---------------------------------------------------------------------------
// bf16 MFMA GEMM: C[M,N] = A[M,K] @ W[N,K]^T  (unchanged from round 3)
// ---------------------------------------------------------------------------
template<bool OBF>
__global__ __launch_bounds__(256) void gemm_bf16(const uint16_t* __restrict__ A,
                                                 const uint16_t* __restrict__ W,
                                                 void* __restrict__ Cout,
                                                 int Nd, int K) {
  __shared__ uint16_t As[128 * 40];
  __shared__ uint16_t Bs[128 * 40];
  const int tid = threadIdx.x;
  const int m0 = blockIdx.x * 128, n0 = blockIdx.y * 128;
  const int l = tid & 63, w = tid >> 6;
  const int wr = (w >> 1) * 64, wc = (w & 1) * 64;
  const int fr = l & 15, fk = (l >> 4) * 8;
  const int srow = tid >> 2, sk = (tid & 3) * 8;
  f32x4 acc[4][4];
#pragma unroll
  for (int mi = 0; mi < 4; ++mi)
#pragma unroll
    for (int nj = 0; nj < 4; ++nj) {
      f32x4 z = {0.f, 0.f, 0.f, 0.f};
      acc[mi][nj] = z;
    }
  const uint16_t* Ap = A + (size_t)(m0 + srow) * K + sk;
  const uint16_t* Wp = W + (size_t)(n0 + srow) * K + sk;
  for (int k0 = 0; k0 < K; k0 += 32) {
    s16x8 a0 = *(const s16x8*)(Ap + k0);
    s16x8 a1 = *(const s16x8*)(Ap + (size_t)64 * K + k0);
    s16x8 b0 = *(const s16x8*)(Wp + k0);
    s16x8 b1 = *(const s16x8*)(Wp + (size_t)64 * K + k0);
    __syncthreads();
    *(s16x8*)&As[srow * 40 + sk]        = a0;
    *(s16x8*)&As[(srow + 64) * 40 + sk] = a1;
    *(s16x8*)&Bs[srow * 40 + sk]        = b0;
    *(s16x8*)&Bs[(srow + 64) * 40 + sk] = b1;
    __syncthreads();
    s16x8 af[4], bfr[4];
#pragma unroll
    for (int mi = 0; mi < 4; ++mi)
      af[mi] = *(const s16x8*)&As[(wr + mi * 16 + fr) * 40 + fk];
#pragma unroll
    for (int nj = 0; nj < 4; ++nj)
      bfr[nj] = *(const s16x8*)&Bs[(wc + nj * 16 + fr) * 40 + fk];
#pragma unroll
    for (int mi = 0; mi < 4; ++mi)
#pragma unroll
      for (int nj = 0; nj < 4; ++nj)
        acc[mi][nj] = __builtin_amdgcn_mfma_f32_16x16x32_bf16(af[mi], bfr[nj],
                                                              acc[mi][nj], 0, 0, 0);
  }
  const int r0 = m0 + wr + (l >> 4) * 4;
  const int c0 = n0 + wc + fr;
#pragma unroll
  for (int mi = 0; mi < 4; ++mi)
#pragma unroll
    for (int nj = 0; nj < 4; ++nj)
#pragma unroll
      for (int p = 0; p < 4; ++p) {
        const int row = r0 + mi * 16 + p;
        const int col = c0 + nj * 16;
        const float val = acc[mi][nj][p];
        if (OBF) ((uint16_t*)Cout)[(size_t)row * Nd + col] = f2b(val);
        else     ((float*)Cout)[(size_t)row * Nd + col]    = val;
      }
}

// ---------------------------------------------------------------------------
// RoPE on bf16 q,k in place; q additionally scaled by dk^-0.5 = 1/16.
// ---------------------------------------------------------------------------
__global__ void rope_kernel(uint16_t* __restrict__ q, uint16_t* __restrict__ k) {
  const int idx = blockIdx.x * 256 + threadIdx.x;   // < B*N*H*128
  const int i = idx & 127;
  const int h = (idx >> 7) & 3;
  const int n = (idx >> 9) & (Nn - 1);
  const int b = idx >> 21;
  const size_t base = ((size_t)(b * Nn + n)) * KEYD + h * DK;
  const float invf = (float)exp((double)i * -0.071955784156063938);  // 1e4^(-i/128)
  const float theta = (float)n * invf;
  float sn, cs;
  sincosf(theta, &sn, &cs);
  float x1 = b2f(q[base + i]), x2 = b2f(q[base + 128 + i]);
  q[base + i]       = f2b((x1 * cs - x2 * sn) * 0.0625f);
  q[base + 128 + i] = f2b((x2 * cs + x1 * sn) * 0.0625f);
  x1 = b2f(k[base + i]); x2 = b2f(k[base + 128 + i]);
  k[base + i]       = f2b(x1 * cs - x2 * sn);
  k[base + 128 + i] = f2b(x2 * cs + x1 * sn);
}

// ---------------------------------------------------------------------------
// Intra-chunk attention (unchanged, known-correct): attn fp32 [bh][c][i][j].
// ---------------------------------------------------------------------------
__global__ __launch_bounds__(256) void attn_kernel(const uint16_t* __restrict__ q,
                                                   const uint16_t* __restrict__ k,
                                                   float* __restrict__ attn) {
  const int c = blockIdx.x & 63;
  const int h = (blockIdx.x >> 6) & 3;
  const int b = blockIdx.x >> 8;
  const int tid = threadIdx.x;
  __shared__ float qs[64][68];
  __shared__ float ks[64][68];
  const int i_  = tid >> 2;
  const int jb  = tid & 3;
  const int lr  = tid >> 2;
  const int lc0 = (tid & 3) * 16;
  float acc[16] = {};
  const uint16_t* qsrc = q + ((size_t)(b * Nn + c * CH + lr)) * KEYD + h * DK + lc0;
  const uint16_t* ksrc = k + ((size_t)(b * Nn + c * CH + lr)) * KEYD + h * DK + lc0;
  for (int dt = 0; dt < 4; ++dt) {
    __syncthreads();
#pragma unroll
    for (int u = 0; u < 2; ++u) {
      uint4 tq = *(const uint4*)(qsrc + dt * 64 + u * 8);
      uint4 tk = *(const uint4*)(ksrc + dt * 64 + u * 8);
      const int cbase = lc0 + u * 8;
      qs[lr][cbase+0] = b2f((uint16_t)tq.x); qs[lr][cbase+1] = b2f((uint16_t)(tq.x>>16));
      qs[lr][cbase+2] = b2f((uint16_t)tq.y); qs[lr][cbase+3] = b2f((uint16_t)(tq.y>>16));
      qs[lr][cbase+4] = b2f((uint16_t)tq.z); qs[lr][cbase+5] = b2f((uint16_t)(tq.z>>16));
      qs[lr][cbase+6] = b2f((uint16_t)tq.w); qs[lr][cbase+7] = b2f((uint16_t)(tq.w>>16));
      ks[lr][cbase+0] = b2f((uint16_t)tk.x); ks[lr][cbase+1] = b2f((uint16_t)(tk.x>>16));
      ks[lr][cbase+2] = b2f((uint16_t)tk.y); ks[lr][cbase+3] = b2f((uint16_t)(tk.y>>16));
      ks[lr][cbase+4] = b2f((uint16_t)tk.z); ks[lr][cbase+5] = b2f((uint16_t)(tk.z>>16));
      ks[lr][cbase+6] = b2f((uint16_t)tk.w); ks[lr][cbase+7] = b2f((uint16_t)(tk.w>>16));
    }
    __syncthreads();
    float4 qr[16];
#pragma unroll
    for (int d4 = 0; d4 < 16; ++d4) qr[d4] = *(const float4*)&qs[i_][d4 * 4];
#pragma unroll
    for (int jj = 0; jj < 16; ++jj) {
      const int j = jb + jj * 4;
      float s = 0.f;
#pragma unroll
      for (int d4 = 0; d4 < 16; ++d4) {
        float4 kk4 = *(const float4*)&ks[j][d4 * 4];
        s = fmaf(qr[d4].x, kk4.x, s); s = fmaf(qr[d4].y, kk4.y, s);
        s = fmaf(qr[d4].z, kk4.z, s); s = fmaf(qr[d4].w, kk4.w, s);
      }
      acc[jj] += s;
    }
  }
  const float gamma = 1.f - exp2f(-5.f - (float)h);
  const float l2g = log2f(gamma);
  float* arow = attn + ((((size_t)b * Hh + h) * NC + c) * CH + i_) * CH;
#pragma unroll
  for (int jj = 0; jj < 16; ++jj) {
    const int j = jb + jj * 4;
    arow[j] = (i_ >= j) ? acc[jj] * exp2f((float)(i_ - j) * l2g) : 0.f;
  }
}

// ---------------------------------------------------------------------------
// Scan decomposition. DV processed in 4 passes of 128 cols; U buffer (32 MiB)
// holds, per (bh,c), the 128x256 slice U^T[w][d] (w = dv col in pass, d = dk).
//
// Kernel A: U_c^T[w,d] = sum_j v[j,w] * (gamma^(63-j) k[j,d])   (MFMA, per (bh,c))
//   M=128(w) x N=256(d) x K=64(j); operands transposed-staged in LDS.
// ---------------------------------------------------------------------------
__global__ __launch_bounds__(256) void chunk_outer(const uint16_t* __restrict__ k,
                                                   const uint16_t* __restrict__ v,
                                                   uint16_t* __restrict__ U, int p) {
  const int c  = blockIdx.x & 63;
  const int bh = blockIdx.x >> 6;
  const int b = bh >> 2, h = bh & 3;
  const int tid = threadIdx.x;
  __shared__ uint16_t kT[256][72];   // [d][j] rows 144B (16B-aligned)
  __shared__ uint16_t vT[128][72];   // [w][j]
  const float l2g = log2f(1.f - exp2f(-5.f - (float)h));
  const int n0 = c * CH;
  {
    const int j = tid >> 2;
    const float gs = exp2f((float)(63 - j) * l2g);   // gamma^(63-j)
    // k^T staging (scaled): 8 x uint4 covering d = (tid&3)*64 .. +63
    const int dbase = (tid & 3) * 64;
    const uint16_t* src = k + ((size_t)(b * Nn + n0 + j)) * KEYD + h * DK + dbase;
#pragma unroll
    for (int u = 0; u < 8; ++u) {
      uint4 t4 = *(const uint4*)(src + u * 8);
      const int d0 = dbase + u * 8;
      uint32_t wv_[4] = {t4.x, t4.y, t4.z, t4.w};
#pragma unroll
      for (int e = 0; e < 4; ++e) {
        kT[d0 + 2*e    ][j] = f2b(b2f((uint16_t)wv_[e]) * gs);
        kT[d0 + 2*e + 1][j] = f2b(b2f((uint16_t)(wv_[e] >> 16)) * gs);
      }
    }
    // v^T staging: 4 x uint4 covering w = (tid&3)*32 .. +31 (pass slice)
    const int wbase = (tid & 3) * 32;
    const uint16_t* vsrc = v + ((size_t)(b * Nn + n0 + j)) * DM + h * DV + p * 128 + wbase;
#pragma unroll
    for (int u = 0; u < 4; ++u) {
      uint4 t4 = *(const uint4*)(vsrc + u * 8);
      const int w0 = wbase + u * 8;
      uint32_t wv_[4] = {t4.x, t4.y, t4.z, t4.w};
#pragma unroll
      for (int e = 0; e < 4; ++e) {
        vT[w0 + 2*e    ][j] = (uint16_t)wv_[e];
        vT[w0 + 2*e + 1][j] = (uint16_t)(wv_[e] >> 16);
      }
    }
  }
  __syncthreads();
  const int l = tid & 63, w = tid >> 6;
  const int wrow = (w >> 1) * 64;     // w' base (M)
  const int wcol = (w & 1) * 128;     // d  base (N)
  const int fr = l & 15, fk = (l >> 4) * 8;
  f32x4 acc[4][8];
#pragma unroll
  for (int mi = 0; mi < 4; ++mi)
#pragma unroll
    for (int nj = 0; nj < 8; ++nj) {
      f32x4 z = {0.f, 0.f, 0.f, 0.f};
      acc[mi][nj] = z;
    }
#pragma unroll
  for (int ks = 0; ks < 2; ++ks) {
    s16x8 af[4], bfr[8];
#pragma unroll
    for (int mi = 0; mi < 4; ++mi)
      af[mi] = *(const s16x8*)&vT[wrow + mi * 16 + fr][ks * 32 + fk];
#pragma unroll
    for (int nj = 0; nj < 8; ++nj)
      bfr[nj] = *(const s16x8*)&kT[wcol + nj * 16 + fr][ks * 32 + fk];
#pragma unroll
    for (int mi = 0; mi < 4; ++mi)
#pragma unroll
      for (int nj = 0; nj < 8; ++nj)
        acc[mi][nj] = __builtin_amdgcn_mfma_f32_16x16x32_bf16(af[mi], bfr[nj],
                                                              acc[mi][nj], 0, 0, 0);
  }
  uint16_t* Ub = U + (size_t)bh * 2097152 + (size_t)c * 32768;
  const int rbase = (l >> 4) * 4;
#pragma unroll
  for (int mi = 0; mi < 4; ++mi)
#pragma unroll
    for (int nj = 0; nj < 8; ++nj)
#pragma unroll
      for (int pp = 0; pp < 4; ++pp) {
        const int wq = wrow + mi * 16 + rbase + pp;
        const int d  = wcol + nj * 16 + fr;
        Ub[(size_t)wq * 256 + d] = f2b(acc[mi][nj][pp]);
      }
}

// ---------------------------------------------------------------------------
// Kernel B: in-place state scan over chunks. Slot c becomes S_c (state BEFORE
// chunk c): S_0 = 0; S_{c+1} = gamma^64 * S_c + U_c. fp32 carried in-register;
// stored snapshots bf16 (errors don't compound).
// ---------------------------------------------------------------------------
__global__ __launch_bounds__(256) void state_scan(uint16_t* __restrict__ U) {
  const int gid = blockIdx.x * 256 + threadIdx.x;   // < 8*32768 = 262144
  const int bh = gid >> 15;
  const int e  = gid & 32767;
  const int h  = bh & 3;
  const float l2g = log2f(1.f - exp2f(-5.f - (float)h));
  const float gC = exp2f(64.f * l2g);
  uint16_t* p = U + (size_t)bh * 2097152 + e;
  float S = 0.f;
#pragma unroll 4
  for (int c = 0; c < 64; ++c) {
    uint16_t* slot = p + (size_t)c * 32768;
    const float u = b2f(*slot);
    *slot = f2b(S);
    S = gC * S + u;
  }
}

// ---------------------------------------------------------------------------
// Kernel C: o[i,w] = (attn_c @ v_c)[i,w] + gamma^(i+1) * (q_c @ S_c)[i,w]
// per (bh,c), pass cols p*128..p*128+127. M=64(i) x N=128(w); K=256 (q@S),
// K=64 (attn@v). q / attn / S^T frags read directly from global; v^T in LDS.
// ---------------------------------------------------------------------------
__global__ __launch_bounds__(256) void scan_out(const uint16_t* __restrict__ q,
                                                const uint16_t* __restrict__ v,
                                                const float* __restrict__ attn,
                                                const uint16_t* __restrict__ U,
                                                float* __restrict__ o, int p) {
  const int c  = blockIdx.x & 63;
  const int bh = blockIdx.x >> 6;
  const int b = bh >> 2, h = bh & 3;
  const int tid = threadIdx.x;
  __shared__ uint16_t vT[128][72];
  __shared__ float gp[65];
  const float l2g = log2f(1.f - exp2f(-5.f - (float)h));
  if (tid < 65) gp[tid] = exp2f((float)tid * l2g);
  const int n0 = c * CH;
  {
    const int j = tid >> 2;
    const int wbase = (tid & 3) * 32;
    const uint16_t* vsrc = v + ((size_t)(b * Nn + n0 + j)) * DM + h * DV + p * 128 + wbase;
#pragma unroll
    for (int u = 0; u < 4; ++u) {
      uint4 t4 = *(const uint4*)(vsrc + u * 8);
      const int w0 = wbase + u * 8;
      uint32_t wv_[4] = {t4.x, t4.y, t4.z, t4.w};
#pragma unroll
      for (int e = 0; e < 4; ++e) {
        vT[w0 + 2*e    ][j] = (uint16_t)wv_[e];
        vT[w0 + 2*e + 1][j] = (uint16_t)(wv_[e] >> 16);
      }
    }
  }
  __syncthreads();
  const int l = tid & 63, wv = tid >> 6;
  const int wcol = wv * 32;                 // output col base (within pass 128)
  const int fr = l & 15, fk = (l >> 4) * 8;
  f32x4 aQS[4][2], aPV[4][2];
#pragma unroll
  for (int mi = 0; mi < 4; ++mi)
#pragma unroll
    for (int nj = 0; nj < 2; ++nj) {
      f32x4 z = {0.f, 0.f, 0.f, 0.f};
      aQS[mi][nj] = z; aPV[mi][nj] = z;
    }
  const uint16_t* qbase = q + ((size_t)(b * Nn + n0)) * KEYD + h * DK;
  const uint16_t* Ub = U + (size_t)bh * 2097152 + (size_t)c * 32768;
  // q @ S  (K = 256)
#pragma unroll
  for (int ks = 0; ks < 8; ++ks) {
    s16x8 qf[4], sf[2];
#pragma unroll
    for (int mi = 0; mi < 4; ++mi)
      qf[mi] = *(const s16x8*)(qbase + (size_t)(mi * 16 + fr) * KEYD + ks * 32 + fk);
#pragma unroll
    for (int nj = 0; nj < 2; ++nj)
      sf[nj] = *(const s16x8*)(Ub + (size_t)(wcol + nj * 16 + fr) * 256 + ks * 32 + fk);
#pragma unroll
    for (int mi = 0; mi < 4; ++mi)
#pragma unroll
      for (int nj = 0; nj < 2; ++nj)
        aQS[mi][nj] = __builtin_amdgcn_mfma_f32_16x16x32_bf16(qf[mi], sf[nj],
                                                              aQS[mi][nj], 0, 0, 0);
  }
  // attn @ v  (K = 64)
  const float* ab = attn + (((size_t)bh * 64 + c) * 64) * 64;
#pragma unroll
  for (int ks = 0; ks < 2; ++ks) {
    s16x8 af[4], vf[2];
#pragma unroll
    for (int mi = 0; mi < 4; ++mi) {
      const float* ar = ab + (size_t)(mi * 16 + fr) * 64 + ks * 32 + fk;
      float4 a0 = *(const float4*)ar;
      float4 a1 = *(const float4*)(ar + 4);
      s16x8 t;
      t[0] = (short)f2b(a0.x); t[1] = (short)f2b(a0.y);
      t[2] = (short)f2b(a0.z); t[3] = (short)f2b(a0.w);
      t[4] = (short)f2b(a1.x); t[5] = (short)f2b(a1.y);
      t[6] = (short)f2b(a1.z); t[7] = (short)f2b(a1.w);
      af[mi] = t;
    }
#pragma unroll
    for (int nj = 0; nj < 2; ++nj)
      vf[nj] = *(const s16x8*)&vT[wcol + nj * 16 + fr][ks * 32 + fk];
#pragma unroll
    for (int mi = 0; mi < 4; ++mi)
#pragma unroll
      for (int nj = 0; nj < 2; ++nj)
        aPV[mi][nj] = __builtin_amdgcn_mfma_f32_16x16x32_bf16(af[mi], vf[nj],
                                                              aPV[mi][nj], 0, 0, 0);
  }
  const int rbase = (l >> 4) * 4;
#pragma unroll
  for (int mi = 0; mi < 4; ++mi)
#pragma unroll
    for (int nj = 0; nj < 2; ++nj)
#pragma unroll
      for (int pp = 0; pp < 4; ++pp) {
        const int i = mi * 16 + rbase + pp;
        const int wc_ = wcol + nj * 16 + fr;
        const float val = aPV[mi][nj][pp] + gp[i + 1] * aQS[mi][nj][pp];
        o[((size_t)(b * Nn + n0 + i)) * DM + h * DV + p * 128 + wc_] = val;
      }
}

// ---------------------------------------------------------------------------
// GroupNorm over DV per (b,n,h) + SiLU gate, in place into bf16 g. (unchanged)
// ---------------------------------------------------------------------------
__global__ __launch_bounds__(256) void gn_gate(const float* __restrict__ o,
                                               uint16_t* __restrict__ g,
                                               const float* __restrict__ gw) {
  const int bn = blockIdx.x;
  const int tid = threadIdx.x;
  const int h = tid >> 6;
  const int lane = tid & 63;
  const size_t base = (size_t)bn * DM + h * DV + lane * 8;
  float4 o0 = *(const float4*)&o[base];
  float4 o1 = *(const float4*)&o[base + 4];
  float ss = o0.x*o0.x + o0.y*o0.y + o0.z*o0.z + o0.w*o0.w
           + o1.x*o1.x + o1.y*o1.y + o1.z*o1.z + o1.w*o1.w;
#pragma unroll
  for (int m = 1; m < 64; m <<= 1) ss += __shfl_xor(ss, m, 64);
  const float r = rsqrtf(ss * (1.f / 512.f) + 1e-5f);
  uint4 gv = *(const uint4*)&g[base];
  float gf[8] = { b2f((uint16_t)gv.x), b2f((uint16_t)(gv.x >> 16)),
                  b2f((uint16_t)gv.y), b2f((uint16_t)(gv.y >> 16)),
                  b2f((uint16_t)gv.z), b2f((uint16_t)(gv.z >> 16)),
                  b2f((uint16_t)gv.w), b2f((uint16_t)(gv.w >> 16)) };
  float ov[8] = { o0.x, o0.y, o0.z, o0.w, o1.x, o1.y, o1.z, o1.w };
  const float* gwp = gw + lane * 8;
  uint16_t res[8];
#pragma unroll
  for (int e = 0; e < 8; ++e) {
    float sil = gf[e] / (1.f + expf(-gf[e]));
    res[e] = f2b(ov[e] * r * gwp[e] * sil);
  }
  uint4 outv;
  outv.x = (uint32_t)res[0] | ((uint32_t)res[1] << 16);
  outv.y = (uint32_t)res[2] | ((uint32_t)res[3] << 16);
  outv.z = (uint32_t)res[4] | ((uint32_t)res[5] << 16);
  outv.w = (uint32_t)res[6] | ((uint32_t)res[7] << 16);
  *(uint4*)&g[base] = outv;
}

// ---------------------------------------------------------------------------
// ws layout (MB), peak 136 (= round-1 proven size):
//   [  0, 16)  qb      [ 16, 32) kb      [ 32, 64) vb
//   [ 64, 72)  attn (fp32)
//   [ 72, 76)  wqb  [76,80) wkb  [80,88) wvb   (dead after phase 1)
//   [ 88, 96)  wgb  [96,104) wob
//   [104,136)  xb (phase 1)  ->  U/S (scan passes, exactly 32 MiB)
// phase 3: xb2 overlays [0,32) (dead qb+kb); gb overlays [32,64) (dead vb).
// o (fp32) lives in d_out until gn_gate; final GEMM overwrites d_out.
// Every region fully rewritten before read each launch -> graph-replay safe.
// ---------------------------------------------------------------------------
extern "C" void kernel_launch(void* const* d_in, const int* in_sizes, int n_in,
                              void* d_out, int out_size, void* d_ws, size_t ws_size,
                              hipStream_t stream) {
  const float* x  = (const float*)d_in[0];
  const float* Wq = (const float*)d_in[1];
  const float* Wk = (const float*)d_in[2];
  const float* Wv = (const float*)d_in[3];
  const float* Wg = (const float*)d_in[4];
  const float* Wo = (const float*)d_in[5];
  const float* gw = (const float*)d_in[6];

  char* base = (char*)d_ws;
  uint16_t* qb   = (uint16_t*)(base);
  uint16_t* kb   = (uint16_t*)(base + ((size_t)16 << 20));
  uint16_t* vb   = (uint16_t*)(base + ((size_t)32 << 20));
  float*    attn = (float*)   (base + ((size_t)64 << 20));
  uint16_t* wqb  = (uint16_t*)(base + ((size_t)72 << 20));
  uint16_t* wkb  = (uint16_t*)(base + ((size_t)76 << 20));
  uint16_t* wvb  = (uint16_t*)(base + ((size_t)80 << 20));
  uint16_t* wgb  = (uint16_t*)(base + ((size_t)88 << 20));
  uint16_t* wob  = (uint16_t*)(base + ((size_t)96 << 20));
  uint16_t* xb   = (uint16_t*)(base + ((size_t)104 << 20));
  uint16_t* Ub   = xb;                     // U/S overlays xb during scan
  uint16_t* xb2  = qb;                     // phase-3 x (overlays dead qb+kb)
  uint16_t* gb   = vb;                     // phase-3 g (overlays dead vb)
  float*    o    = (float*)d_out;          // scratch until gn_gate

  dim3 blk(256);
  conv_f2b<<<dim3(8192), blk, 0, stream>>>(x,  xb,  M * DM / 8);
  conv_f2b<<<dim3(1024), blk, 0, stream>>>(Wq, wqb, KEYD * DM / 8);
  conv_f2b<<<dim3(1024), blk, 0, stream>>>(Wk, wkb, KEYD * DM / 8);
  conv_f2b<<<dim3(2048), blk, 0, stream>>>(Wv, wvb, DM * DM / 8);
  conv_f2b<<<dim3(2048), blk, 0, stream>>>(Wg, wgb, DM * DM / 8);
  conv_f2b<<<dim3(2048), blk, 0, stream>>>(Wo, wob, DM * DM / 8);
  gemm_bf16<true><<<dim3(M/128, KEYD/128), blk, 0, stream>>>(xb, wqb, qb, KEYD, DM);
  gemm_bf16<true><<<dim3(M/128, KEYD/128), blk, 0, stream>>>(xb, wkb, kb, KEYD, DM);
  gemm_bf16<true><<<dim3(M/128, DM/128),   blk, 0, stream>>>(xb, wvb, vb, DM, DM);
  rope_kernel<<<dim3((Bb*Nn*Hh*128)/256), blk, 0, stream>>>(qb, kb);
  attn_kernel<<<dim3(Bb*Hh*NC), blk, 0, stream>>>(qb, kb, attn);
  // xb dead from here; U/S overlays it
  for (int p = 0; p < 4; ++p) {
    chunk_outer<<<dim3(Bb*Hh*NC),  blk, 0, stream>>>(kb, vb, Ub, p);
    state_scan<<<dim3(1024),       blk, 0, stream>>>(Ub);
    scan_out<<<dim3(Bb*Hh*NC),     blk, 0, stream>>>(qb, vb, attn, Ub, o, p);
  }
  // phase 3: qb/kb/vb dead
  conv_f2b<<<dim3(8192), blk, 0, stream>>>(x, xb2, M * DM / 8);
  gemm_bf16<true><<<dim3(M/128, DM/128),  blk, 0, stream>>>(xb2, wgb, gb, DM, DM);
  gn_gate<<<dim3(M), blk, 0, stream>>>(o, gb, gw);
  gemm_bf16<false><<<dim3(M/128, DM/128), blk, 0, stream>>>(gb, wob, (float*)d_out, DM, DM);
}

// Round 5
// 741.237 us; speedup vs baseline: 6.6177x; 1.0040x over previous
//
#include <hip/hip_runtime.h>
#include <hip/hip_bf16.h>
#include <stdint.h>

// Problem constants (MultiScaleRetention: B=2, N=4096, D_MODEL=2048, H=4)
constexpr int Bb   = 2;
constexpr int Nn   = 4096;
constexpr int DM   = 2048;
constexpr int Hh   = 4;
constexpr int DK   = 256;    // KEY_DIM / H
constexpr int DV   = 512;    // D_MODEL / H
constexpr int KEYD = 1024;
constexpr int CH   = 64;     // chunk
constexpr int NC   = Nn / CH;   // 64 chunks
constexpr int M    = Bb * Nn;   // 8192 rows

typedef __attribute__((ext_vector_type(8))) short s16x8;   // 8 bf16 (4 VGPRs)
typedef __attribute__((ext_vector_type(4))) float f32x4;

__device__ __forceinline__ float b2f(uint16_t h) {
  return __uint_as_float(((uint32_t)h) << 16);
}
__device__ __forceinline__ uint16_t f2b(float f) {   // RNE, finite inputs
  uint32_t u = __float_as_uint(f);
  return (uint16_t)((u + 0x7fffu + ((u >> 16) & 1u)) >> 16);
}

// async global->LDS, 16B per lane; LDS dest = wave-uniform base + lane*16
__device__ __forceinline__ void gload16(const void* g, void* l) {
  __builtin_amdgcn_global_load_lds(
      (const __attribute__((address_space(1))) void*)g,
      (__attribute__((address_space(3))) void*)l, 16, 0, 0);
}

// ---------------------------------------------------------------------------
// fp32 -> bf16 bulk convert, 8 elems/thread
// ---------------------------------------------------------------------------
__global__ __launch_bounds__(256) void conv_f2b(const float* __restrict__ s,
                                                uint16_t* __restrict__ d, int n8) {
  int i = blockIdx.x * 256 + threadIdx.x;
  if (i >= n8) return;
  const float4* sp = (const float4*)s;
  float4 a = sp[2 * i], b = sp[2 * i + 1];
  uint4 o;
  o.x = (uint32_t)f2b(a.x) | ((uint32_t)f2b(a.y) << 16);
  o.y = (uint32_t)f2b(a.z) | ((uint32_t)f2b(a.w) << 16);
  o.z = (uint32_t)f2b(b.x) | ((uint32_t)f2b(b.y) << 16);
  o.w = (uint32_t)f2b(b.z) | ((uint32_t)f2b(b.w) << 16);
  ((uint4*)d)[i] = o;
}

// ---------------------------------------------------------------------------
// bf16 MFMA GEMM: C[M,N] = A[M,K] @ W[N,K]^T  — m97 structure:
// linear LDS [128][32] (no pad), global_load_lds width=16 staging (chunk =
// tid for round 0, 256+tid for round 1 -> LDS fills in exact lane order),
// 2-barrier K-loop, BK=32, 4 waves (2x2), 4x4 frags of 16x16x32.
// C/D: col=lane&15, row=(lane>>4)*4+reg (m89/m91-verified, round-3-proven).
// ---------------------------------------------------------------------------
template<bool OBF>
__global__ __launch_bounds__(256) void gemm_bf16(const uint16_t* __restrict__ A,
                                                 const uint16_t* __restrict__ W,
                                                 void* __restrict__ Cout,
                                                 int Nd, int K) {
  __shared__ uint16_t As[128 * 32];
  __shared__ uint16_t Bs[128 * 32];
  const int tid = threadIdx.x;
  const int m0 = blockIdx.x * 128, n0 = blockIdx.y * 128;
  const int l = tid & 63, w = tid >> 6;
  const int wr = (w >> 1) * 64, wc = (w & 1) * 64;
  const int fr = l & 15, fk = (l >> 4) * 8;
  const int srow = tid >> 2, sk = (tid & 3) * 8;   // chunk tid -> (row, k8)
  f32x4 acc[4][4];
#pragma unroll
  for (int mi = 0; mi < 4; ++mi)
#pragma unroll
    for (int nj = 0; nj < 4; ++nj) {
      f32x4 z = {0.f, 0.f, 0.f, 0.f};
      acc[mi][nj] = z;
    }
  const uint16_t* Ap = A + (size_t)(m0 + srow) * K + sk;   // round 0 (rows 0..63)
  const uint16_t* Wp = W + (size_t)(n0 + srow) * K + sk;
  // wave-uniform LDS bases: round r, wave w -> chunk (r*256 + w*64), *8 bf16
  uint16_t* AsW0 = As + w * 512;
  uint16_t* AsW1 = As + 2048 + w * 512;
  uint16_t* BsW0 = Bs + w * 512;
  uint16_t* BsW1 = Bs + 2048 + w * 512;
  for (int k0 = 0; k0 < K; k0 += 32) {
    __syncthreads();                       // prior tile fully consumed
    gload16(Ap + k0, AsW0);
    gload16(Ap + (size_t)64 * K + k0, AsW1);
    gload16(Wp + k0, BsW0);
    gload16(Wp + (size_t)64 * K + k0, BsW1);
    __syncthreads();                       // drains vmcnt -> tile ready
    s16x8 af[4], bfr[4];
#pragma unroll
    for (int mi = 0; mi < 4; ++mi)
      af[mi] = *(const s16x8*)&As[(wr + mi * 16 + fr) * 32 + fk];
#pragma unroll
    for (int nj = 0; nj < 4; ++nj)
      bfr[nj] = *(const s16x8*)&Bs[(wc + nj * 16 + fr) * 32 + fk];
#pragma unroll
    for (int mi = 0; mi < 4; ++mi)
#pragma unroll
      for (int nj = 0; nj < 4; ++nj)
        acc[mi][nj] = __builtin_amdgcn_mfma_f32_16x16x32_bf16(af[mi], bfr[nj],
                                                              acc[mi][nj], 0, 0, 0);
  }
  const int r0 = m0 + wr + (l >> 4) * 4;
  const int c0 = n0 + wc + fr;
#pragma unroll
  for (int mi = 0; mi < 4; ++mi)
#pragma unroll
    for (int nj = 0; nj < 4; ++nj)
#pragma unroll
      for (int p = 0; p < 4; ++p) {
        const int row = r0 + mi * 16 + p;
        const int col = c0 + nj * 16;
        const float val = acc[mi][nj][p];
        if (OBF) ((uint16_t*)Cout)[(size_t)row * Nd + col] = f2b(val);
        else     ((float*)Cout)[(size_t)row * Nd + col]    = val;
      }
}

// ---------------------------------------------------------------------------
// RoPE on bf16 q,k in place; q additionally scaled by dk^-0.5 = 1/16.
// ---------------------------------------------------------------------------
__global__ void rope_kernel(uint16_t* __restrict__ q, uint16_t* __restrict__ k) {
  const int idx = blockIdx.x * 256 + threadIdx.x;   // < B*N*H*128
  const int i = idx & 127;
  const int h = (idx >> 7) & 3;
  const int n = (idx >> 9) & (Nn - 1);
  const int b = idx >> 21;
  const size_t base = ((size_t)(b * Nn + n)) * KEYD + h * DK;
  const float invf = (float)exp((double)i * -0.071955784156063938);  // 1e4^(-i/128)
  const float theta = (float)n * invf;
  float sn, cs;
  sincosf(theta, &sn, &cs);
  float x1 = b2f(q[base + i]), x2 = b2f(q[base + 128 + i]);
  q[base + i]       = f2b((x1 * cs - x2 * sn) * 0.0625f);
  q[base + 128 + i] = f2b((x2 * cs + x1 * sn) * 0.0625f);
  x1 = b2f(k[base + i]); x2 = b2f(k[base + 128 + i]);
  k[base + i]       = f2b(x1 * cs - x2 * sn);
  k[base + 128 + i] = f2b(x2 * cs + x1 * sn);
}

// ---------------------------------------------------------------------------
// Intra-chunk attention (unchanged, known-correct): attn fp32 [bh][c][i][j].
// ---------------------------------------------------------------------------
__global__ __launch_bounds__(256) void attn_kernel(const uint16_t* __restrict__ q,
                                                   const uint16_t* __restrict__ k,
                                                   float* __restrict__ attn) {
  const int c = blockIdx.x & 63;
  const int h = (blockIdx.x >> 6) & 3;
  const int b = blockIdx.x >> 8;
  const int tid = threadIdx.x;
  __shared__ float qs[64][68];
  __shared__ float ks[64][68];
  const int i_  = tid >> 2;
  const int jb  = tid & 3;
  const int lr  = tid >> 2;
  const int lc0 = (tid & 3) * 16;
  float acc[16] = {};
  const uint16_t* qsrc = q + ((size_t)(b * Nn + c * CH + lr)) * KEYD + h * DK + lc0;
  const uint16_t* ksrc = k + ((size_t)(b * Nn + c * CH + lr)) * KEYD + h * DK + lc0;
  for (int dt = 0; dt < 4; ++dt) {
    __syncthreads();
#pragma unroll
    for (int u = 0; u < 2; ++u) {
      uint4 tq = *(const uint4*)(qsrc + dt * 64 + u * 8);
      uint4 tk = *(const uint4*)(ksrc + dt * 64 + u * 8);
      const int cbase = lc0 + u * 8;
      qs[lr][cbase+0] = b2f((uint16_t)tq.x); qs[lr][cbase+1] = b2f((uint16_t)(tq.x>>16));
      qs[lr][cbase+2] = b2f((uint16_t)tq.y); qs[lr][cbase+3] = b2f((uint16_t)(tq.y>>16));
      qs[lr][cbase+4] = b2f((uint16_t)tq.z); qs[lr][cbase+5] = b2f((uint16_t)(tq.z>>16));
      qs[lr][cbase+6] = b2f((uint16_t)tq.w); qs[lr][cbase+7] = b2f((uint16_t)(tq.w>>16));
      ks[lr][cbase+0] = b2f((uint16_t)tk.x); ks[lr][cbase+1] = b2f((uint16_t)(tk.x>>16));
      ks[lr][cbase+2] = b2f((uint16_t)tk.y); ks[lr][cbase+3] = b2f((uint16_t)(tk.y>>16));
      ks[lr][cbase+4] = b2f((uint16_t)tk.z); ks[lr][cbase+5] = b2f((uint16_t)(tk.z>>16));
      ks[lr][cbase+6] = b2f((uint16_t)tk.w); ks[lr][cbase+7] = b2f((uint16_t)(tk.w>>16));
    }
    __syncthreads();
    float4 qr[16];
#pragma unroll
    for (int d4 = 0; d4 < 16; ++d4) qr[d4] = *(const float4*)&qs[i_][d4 * 4];
#pragma unroll
    for (int jj = 0; jj < 16; ++jj) {
      const int j = jb + jj * 4;
      float s = 0.f;
#pragma unroll
      for (int d4 = 0; d4 < 16; ++d4) {
        float4 kk4 = *(const float4*)&ks[j][d4 * 4];
        s = fmaf(qr[d4].x, kk4.x, s); s = fmaf(qr[d4].y, kk4.y, s);
        s = fmaf(qr[d4].z, kk4.z, s); s = fmaf(qr[d4].w, kk4.w, s);
      }
      acc[jj] += s;
    }
  }
  const float gamma = 1.f - exp2f(-5.f - (float)h);
  const float l2g = log2f(gamma);
  float* arow = attn + ((((size_t)b * Hh + h) * NC + c) * CH + i_) * CH;
#pragma unroll
  for (int jj = 0; jj < 16; ++jj) {
    const int j = jb + jj * 4;
    arow[j] = (i_ >= j) ? acc[jj] * exp2f((float)(i_ - j) * l2g) : 0.f;
  }
}

// ---------------------------------------------------------------------------
// Scan decomposition. DV processed in 4 passes of 128 cols; U buffer (32 MiB)
// holds, per (bh,c), the 128x256 slice U^T[w][d] (w = dv col in pass, d = dk).
//
// Kernel A: U_c^T[w,d] = sum_j v[j,w] * (gamma^(63-j) k[j,d])   (MFMA, per (bh,c))
// ---------------------------------------------------------------------------
__global__ __launch_bounds__(256) void chunk_outer(const uint16_t* __restrict__ k,
                                                   const uint16_t* __restrict__ v,
                                                   uint16_t* __restrict__ U, int p) {
  const int c  = blockIdx.x & 63;
  const int bh = blockIdx.x >> 6;
  const int b = bh >> 2, h = bh & 3;
  const int tid = threadIdx.x;
  __shared__ uint16_t kT[256][72];   // [d][j] rows 144B (16B-aligned)
  __shared__ uint16_t vT[128][72];   // [w][j]
  const float l2g = log2f(1.f - exp2f(-5.f - (float)h));
  const int n0 = c * CH;
  {
    const int j = tid >> 2;
    const float gs = exp2f((float)(63 - j) * l2g);   // gamma^(63-j)
    // k^T staging (scaled): 8 x uint4 covering d = (tid&3)*64 .. +63
    const int dbase = (tid & 3) * 64;
    const uint16_t* src = k + ((size_t)(b * Nn + n0 + j)) * KEYD + h * DK + dbase;
#pragma unroll
    for (int u = 0; u < 8; ++u) {
      uint4 t4 = *(const uint4*)(src + u * 8);
      const int d0 = dbase + u * 8;
      uint32_t wv_[4] = {t4.x, t4.y, t4.z, t4.w};
#pragma unroll
      for (int e = 0; e < 4; ++e) {
        kT[d0 + 2*e    ][j] = f2b(b2f((uint16_t)wv_[e]) * gs);
        kT[d0 + 2*e + 1][j] = f2b(b2f((uint16_t)(wv_[e] >> 16)) * gs);
      }
    }
    // v^T staging: 4 x uint4 covering w = (tid&3)*32 .. +31 (pass slice)
    const int wbase = (tid & 3) * 32;
    const uint16_t* vsrc = v + ((size_t)(b * Nn + n0 + j)) * DM + h * DV + p * 128 + wbase;
#pragma unroll
    for (int u = 0; u < 4; ++u) {
      uint4 t4 = *(const uint4*)(vsrc + u * 8);
      const int w0 = wbase + u * 8;
      uint32_t wv_[4] = {t4.x, t4.y, t4.z, t4.w};
#pragma unroll
      for (int e = 0; e < 4; ++e) {
        vT[w0 + 2*e    ][j] = (uint16_t)wv_[e];
        vT[w0 + 2*e + 1][j] = (uint16_t)(wv_[e] >> 16);
      }
    }
  }
  __syncthreads();
  const int l = tid & 63, w = tid >> 6;
  const int wrow = (w >> 1) * 64;     // w' base (M)
  const int wcol = (w & 1) * 128;     // d  base (N)
  const int fr = l & 15, fk = (l >> 4) * 8;
  f32x4 acc[4][8];
#pragma unroll
  for (int mi = 0; mi < 4; ++mi)
#pragma unroll
    for (int nj = 0; nj < 8; ++nj) {
      f32x4 z = {0.f, 0.f, 0.f, 0.f};
      acc[mi][nj] = z;
    }
#pragma unroll
  for (int ks = 0; ks < 2; ++ks) {
    s16x8 af[4], bfr[8];
#pragma unroll
    for (int mi = 0; mi < 4; ++mi)
      af[mi] = *(const s16x8*)&vT[wrow + mi * 16 + fr][ks * 32 + fk];
#pragma unroll
    for (int nj = 0; nj < 8; ++nj)
      bfr[nj] = *(const s16x8*)&kT[wcol + nj * 16 + fr][ks * 32 + fk];
#pragma unroll
    for (int mi = 0; mi < 4; ++mi)
#pragma unroll
      for (int nj = 0; nj < 8; ++nj)
        acc[mi][nj] = __builtin_amdgcn_mfma_f32_16x16x32_bf16(af[mi], bfr[nj],
                                                              acc[mi][nj], 0, 0, 0);
  }
  uint16_t* Ub = U + (size_t)bh * 2097152 + (size_t)c * 32768;
  const int rbase = (l >> 4) * 4;
#pragma unroll
  for (int mi = 0; mi < 4; ++mi)
#pragma unroll
    for (int nj = 0; nj < 8; ++nj)
#pragma unroll
      for (int pp = 0; pp < 4; ++pp) {
        const int wq = wrow + mi * 16 + rbase + pp;
        const int d  = wcol + nj * 16 + fr;
        Ub[(size_t)wq * 256 + d] = f2b(acc[mi][nj][pp]);
      }
}

// ---------------------------------------------------------------------------
// Kernel B: in-place state scan over chunks. Slot c becomes S_c (state BEFORE
// chunk c): S_0 = 0; S_{c+1} = gamma^64 * S_c + U_c. fp32 carried in-register;
// stored snapshots bf16 (errors don't compound).
// ---------------------------------------------------------------------------
__global__ __launch_bounds__(256) void state_scan(uint16_t* __restrict__ U) {
  const int gid = blockIdx.x * 256 + threadIdx.x;   // < 8*32768 = 262144
  const int bh = gid >> 15;
  const int e  = gid & 32767;
  const int h  = bh & 3;
  const float l2g = log2f(1.f - exp2f(-5.f - (float)h));
  const float gC = exp2f(64.f * l2g);
  uint16_t* p = U + (size_t)bh * 2097152 + e;
  float S = 0.f;
#pragma unroll 4
  for (int c = 0; c < 64; ++c) {
    uint16_t* slot = p + (size_t)c * 32768;
    const float u = b2f(*slot);
    *slot = f2b(S);
    S = gC * S + u;
  }
}

// ---------------------------------------------------------------------------
// Kernel C: o[i,w] = (attn_c @ v_c)[i,w] + gamma^(i+1) * (q_c @ S_c)[i,w]
// ---------------------------------------------------------------------------
__global__ __launch_bounds__(256) void scan_out(const uint16_t* __restrict__ q,
                                                const uint16_t* __restrict__ v,
                                                const float* __restrict__ attn,
                                                const uint16_t* __restrict__ U,
                                                float* __restrict__ o, int p) {
  const int c  = blockIdx.x & 63;
  const int bh = blockIdx.x >> 6;
  const int b = bh >> 2, h = bh & 3;
  const int tid = threadIdx.x;
  __shared__ uint16_t vT[128][72];
  __shared__ float gp[65];
  const float l2g = log2f(1.f - exp2f(-5.f - (float)h));
  if (tid < 65) gp[tid] = exp2f((float)tid * l2g);
  const int n0 = c * CH;
  {
    const int j = tid >> 2;
    const int wbase = (tid & 3) * 32;
    const uint16_t* vsrc = v + ((size_t)(b * Nn + n0 + j)) * DM + h * DV + p * 128 + wbase;
#pragma unroll
    for (int u = 0; u < 4; ++u) {
      uint4 t4 = *(const uint4*)(vsrc + u * 8);
      const int w0 = wbase + u * 8;
      uint32_t wv_[4] = {t4.x, t4.y, t4.z, t4.w};
#pragma unroll
      for (int e = 0; e < 4; ++e) {
        vT[w0 + 2*e    ][j] = (uint16_t)wv_[e];
        vT[w0 + 2*e + 1][j] = (uint16_t)(wv_[e] >> 16);
      }
    }
  }
  __syncthreads();
  const int l = tid & 63, wv = tid >> 6;
  const int wcol = wv * 32;                 // output col base (within pass 128)
  const int fr = l & 15, fk = (l >> 4) * 8;
  f32x4 aQS[4][2], aPV[4][2];
#pragma unroll
  for (int mi = 0; mi < 4; ++mi)
#pragma unroll
    for (int nj = 0; nj < 2; ++nj) {
      f32x4 z = {0.f, 0.f, 0.f, 0.f};
      aQS[mi][nj] = z; aPV[mi][nj] = z;
    }
  const uint16_t* qbase = q + ((size_t)(b * Nn + n0)) * KEYD + h * DK;
  const uint16_t* Ub = U + (size_t)bh * 2097152 + (size_t)c * 32768;
  // q @ S  (K = 256)
#pragma unroll
  for (int ks = 0; ks < 8; ++ks) {
    s16x8 qf[4], sf[2];
#pragma unroll
    for (int mi = 0; mi < 4; ++mi)
      qf[mi] = *(const s16x8*)(qbase + (size_t)(mi * 16 + fr) * KEYD + ks * 32 + fk);
#pragma unroll
    for (int nj = 0; nj < 2; ++nj)
      sf[nj] = *(const s16x8*)(Ub + (size_t)(wcol + nj * 16 + fr) * 256 + ks * 32 + fk);
#pragma unroll
    for (int mi = 0; mi < 4; ++mi)
#pragma unroll
      for (int nj = 0; nj < 2; ++nj)
        aQS[mi][nj] = __builtin_amdgcn_mfma_f32_16x16x32_bf16(qf[mi], sf[nj],
                                                              aQS[mi][nj], 0, 0, 0);
  }
  // attn @ v  (K = 64)
  const float* ab = attn + (((size_t)bh * 64 + c) * 64) * 64;
#pragma unroll
  for (int ks = 0; ks < 2; ++ks) {
    s16x8 af[4], vf[2];
#pragma unroll
    for (int mi = 0; mi < 4; ++mi) {
      const float* ar = ab + (size_t)(mi * 16 + fr) * 64 + ks * 32 + fk;
      float4 a0 = *(const float4*)ar;
      float4 a1 = *(const float4*)(ar + 4);
      s16x8 t;
      t[0] = (short)f2b(a0.x); t[1] = (short)f2b(a0.y);
      t[2] = (short)f2b(a0.z); t[3] = (short)f2b(a0.w);
      t[4] = (short)f2b(a1.x); t[5] = (short)f2b(a1.y);
      t[6] = (short)f2b(a1.z); t[7] = (short)f2b(a1.w);
      af[mi] = t;
    }
#pragma unroll
    for (int nj = 0; nj < 2; ++nj)
      vf[nj] = *(const s16x8*)&vT[wcol + nj * 16 + fr][ks * 32 + fk];
#pragma unroll
    for (int mi = 0; mi < 4; ++mi)
#pragma unroll
      for (int nj = 0; nj < 2; ++nj)
        aPV[mi][nj] = __builtin_amdgcn_mfma_f32_16x16x32_bf16(af[mi], vf[nj],
                                                              aPV[mi][nj], 0, 0, 0);
  }
  const int rbase = (l >> 4) * 4;
#pragma unroll
  for (int mi = 0; mi < 4; ++mi)
#pragma unroll
    for (int nj = 0; nj < 2; ++nj)
#pragma unroll
      for (int pp = 0; pp < 4; ++pp) {
        const int i = mi * 16 + rbase + pp;
        const int wc_ = wcol + nj * 16 + fr;
        const float val = aPV[mi][nj][pp] + gp[i + 1] * aQS[mi][nj][pp];
        o[((size_t)(b * Nn + n0 + i)) * DM + h * DV + p * 128 + wc_] = val;
      }
}

// ---------------------------------------------------------------------------
// GroupNorm over DV per (b,n,h) + SiLU gate, in place into bf16 g. (unchanged)
// ---------------------------------------------------------------------------
__global__ __launch_bounds__(256) void gn_gate(const float* __restrict__ o,
                                               uint16_t* __restrict__ g,
                                               const float* __restrict__ gw) {
  const int bn = blockIdx.x;
  const int tid = threadIdx.x;
  const int h = tid >> 6;
  const int lane = tid & 63;
  const size_t base = (size_t)bn * DM + h * DV + lane * 8;
  float4 o0 = *(const float4*)&o[base];
  float4 o1 = *(const float4*)&o[base + 4];
  float ss = o0.x*o0.x + o0.y*o0.y + o0.z*o0.z + o0.w*o0.w
           + o1.x*o1.x + o1.y*o1.y + o1.z*o1.z + o1.w*o1.w;
#pragma unroll
  for (int m = 1; m < 64; m <<= 1) ss += __shfl_xor(ss, m, 64);
  const float r = rsqrtf(ss * (1.f / 512.f) + 1e-5f);
  uint4 gv = *(const uint4*)&g[base];
  float gf[8] = { b2f((uint16_t)gv.x), b2f((uint16_t)(gv.x >> 16)),
                  b2f((uint16_t)gv.y), b2f((uint16_t)(gv.y >> 16)),
                  b2f((uint16_t)gv.z), b2f((uint16_t)(gv.z >> 16)),
                  b2f((uint16_t)gv.w), b2f((uint16_t)(gv.w >> 16)) };
  float ov[8] = { o0.x, o0.y, o0.z, o0.w, o1.x, o1.y, o1.z, o1.w };
  const float* gwp = gw + lane * 8;
  uint16_t res[8];
#pragma unroll
  for (int e = 0; e < 8; ++e) {
    float sil = gf[e] / (1.f + expf(-gf[e]));
    res[e] = f2b(ov[e] * r * gwp[e] * sil);
  }
  uint4 outv;
  outv.x = (uint32_t)res[0] | ((uint32_t)res[1] << 16);
  outv.y = (uint32_t)res[2] | ((uint32_t)res[3] << 16);
  outv.z = (uint32_t)res[4] | ((uint32_t)res[5] << 16);
  outv.w = (uint32_t)res[6] | ((uint32_t)res[7] << 16);
  *(uint4*)&g[base] = outv;
}

// ---------------------------------------------------------------------------
// ws layout (MB), peak 136 (= round-1 proven size):
//   [  0, 16)  qb      [ 16, 32) kb      [ 32, 64) vb
//   [ 64, 72)  attn (fp32)
//   [ 72, 76)  wqb  [76,80) wkb  [80,88) wvb   (dead after phase 1)
//   [ 88, 96)  wgb  [96,104) wob
//   [104,136)  xb (phase 1)  ->  U/S (scan passes, exactly 32 MiB)
// phase 3: xb2 overlays [0,32) (dead qb+kb); gb overlays [32,64) (dead vb).
// o (fp32) lives in d_out until gn_gate; final GEMM overwrites d_out.
// Every region fully rewritten before read each launch -> graph-replay safe.
// ---------------------------------------------------------------------------
extern "C" void kernel_launch(void* const* d_in, const int* in_sizes, int n_in,
                              void* d_out, int out_size, void* d_ws, size_t ws_size,
                              hipStream_t stream) {
  const float* x  = (const float*)d_in[0];
  const float* Wq = (const float*)d_in[1];
  const float* Wk = (const float*)d_in[2];
  const float* Wv = (const float*)d_in[3];
  const float* Wg = (const float*)d_in[4];
  const float* Wo = (const float*)d_in[5];
  const float* gw = (const float*)d_in[6];

  char* base = (char*)d_ws;
  uint16_t* qb   = (uint16_t*)(base);
  uint16_t* kb   = (uint16_t*)(base + ((size_t)16 << 20));
  uint16_t* vb   = (uint16_t*)(base + ((size_t)32 << 20));
  float*    attn = (float*)   (base + ((size_t)64 << 20));
  uint16_t* wqb  = (uint16_t*)(base + ((size_t)72 << 20));
  uint16_t* wkb  = (uint16_t*)(base + ((size_t)76 << 20));
  uint16_t* wvb  = (uint16_t*)(base + ((size_t)80 << 20));
  uint16_t* wgb  = (uint16_t*)(base + ((size_t)88 << 20));
  uint16_t* wob  = (uint16_t*)(base + ((size_t)96 << 20));
  uint16_t* xb   = (uint16_t*)(base + ((size_t)104 << 20));
  uint16_t* Ub   = xb;                     // U/S overlays xb during scan
  uint16_t* xb2  = qb;                     // phase-3 x (overlays dead qb+kb)
  uint16_t* gb   = vb;                     // phase-3 g (overlays dead vb)
  float*    o    = (float*)d_out;          // scratch until gn_gate

  dim3 blk(256);
  conv_f2b<<<dim3(8192), blk, 0, stream>>>(x,  xb,  M * DM / 8);
  conv_f2b<<<dim3(1024), blk, 0, stream>>>(Wq, wqb, KEYD * DM / 8);
  conv_f2b<<<dim3(1024), blk, 0, stream>>>(Wk, wkb, KEYD * DM / 8);
  conv_f2b<<<dim3(2048), blk, 0, stream>>>(Wv, wvb, DM * DM / 8);
  conv_f2b<<<dim3(2048), blk, 0, stream>>>(Wg, wgb, DM * DM / 8);
  conv_f2b<<<dim3(2048), blk, 0, stream>>>(Wo, wob, DM * DM / 8);
  gemm_bf16<true><<<dim3(M/128, KEYD/128), blk, 0, stream>>>(xb, wqb, qb, KEYD, DM);
  gemm_bf16<true><<<dim3(M/128, KEYD/128), blk, 0, stream>>>(xb, wkb, kb, KEYD, DM);
  gemm_bf16<true><<<dim3(M/128, DM/128),   blk, 0, stream>>>(xb, wvb, vb, DM, DM);
  rope_kernel<<<dim3((Bb*Nn*Hh*128)/256), blk, 0, stream>>>(qb, kb);
  attn_kernel<<<dim3(Bb*Hh*NC), blk, 0, stream>>>(qb, kb, attn);
  // xb dead from here; U/S overlays it
  for (int p = 0; p < 4; ++p) {
    chunk_outer<<<dim3(Bb*Hh*NC),  blk, 0, stream>>>(kb, vb, Ub, p);
    state_scan<<<dim3(1024),       blk, 0, stream>>>(Ub);
    scan_out<<<dim3(Bb*Hh*NC),     blk, 0, stream>>>(qb, vb, attn, Ub, o, p);
  }
  // phase 3: qb/kb/vb dead
  conv_f2b<<<dim3(8192), blk, 0, stream>>>(x, xb2, M * DM / 8);
  gemm_bf16<true><<<dim3(M/128, DM/128),  blk, 0, stream>>>(xb2, wgb, gb, DM, DM);
  gn_gate<<<dim3(M), blk, 0, stream>>>(o, gb, gw);
  gemm_bf16<false><<<dim3(M/128, DM/128), blk, 0, stream>>>(gb, wob, (float*)d_out, DM, DM);
}

// Round 6
// 675.213 us; speedup vs baseline: 7.2647x; 1.0978x over previous
//
#include <hip/hip_runtime.h>
#include <hip/hip_bf16.h>
#include <stdint.h>

// Problem constants (MultiScaleRetention: B=2, N=4096, D_MODEL=2048, H=4)
constexpr int Bb   = 2;
constexpr int Nn   = 4096;
constexpr int DM   = 2048;
constexpr int Hh   = 4;
constexpr int DK   = 256;    // KEY_DIM / H
constexpr int DV   = 512;    // D_MODEL / H
constexpr int QKS  = 2048;   // fused q|k row stride (q cols 0-1023, k cols 1024-2047)
constexpr int CH   = 64;     // chunk
constexpr int NC   = Nn / CH;   // 64 chunks
constexpr int M    = Bb * Nn;   // 8192 rows

typedef __attribute__((ext_vector_type(8))) short s16x8;   // 8 bf16 (4 VGPRs)
typedef __attribute__((ext_vector_type(4))) float f32x4;

__device__ __forceinline__ float b2f(uint16_t h) {
  return __uint_as_float(((uint32_t)h) << 16);
}
__device__ __forceinline__ uint16_t f2b(float f) {   // RNE, finite inputs
  uint32_t u = __float_as_uint(f);
  return (uint16_t)((u + 0x7fffu + ((u >> 16) & 1u)) >> 16);
}

// async global->LDS, 16B per lane; LDS dest = wave-uniform base + lane*16
__device__ __forceinline__ void gload16(const void* g, void* l) {
  __builtin_amdgcn_global_load_lds(
      (const __attribute__((address_space(1))) void*)g,
      (__attribute__((address_space(3))) void*)l, 16, 0, 0);
}

// ---------------------------------------------------------------------------
// fp32 -> bf16 bulk convert, 8 elems/thread
// ---------------------------------------------------------------------------
__global__ __launch_bounds__(256) void conv_f2b(const float* __restrict__ s,
                                                uint16_t* __restrict__ d, int n8) {
  int i = blockIdx.x * 256 + threadIdx.x;
  if (i >= n8) return;
  const float4* sp = (const float4*)s;
  float4 a = sp[2 * i], b = sp[2 * i + 1];
  uint4 o;
  o.x = (uint32_t)f2b(a.x) | ((uint32_t)f2b(a.y) << 16);
  o.y = (uint32_t)f2b(a.z) | ((uint32_t)f2b(a.w) << 16);
  o.z = (uint32_t)f2b(b.x) | ((uint32_t)f2b(b.y) << 16);
  o.w = (uint32_t)f2b(b.z) | ((uint32_t)f2b(b.w) << 16);
  ((uint4*)d)[i] = o;
}

// ---------------------------------------------------------------------------
// 256x256 bf16 MFMA GEMM, 2-phase double-buffered (T3-minimum recipe):
// C[M,N] = A[M,K] @ W[N,K]^T. BK=32, 512 thr = 8 waves (2Mx4N), wave tile
// 128x64 = 8x4 frags of 16x16x32. LDS 2x(16+16) KB linear [256][32], staged
// via global_load_lds w16 (chunk c = r*8+w covers rows c*16..+15; lane l ->
// row c*16 + (l>>2), col (l&3)*8 — matches linear lane-order fill).
// Loop: STAGE(t+1, buf^1) BEFORE compute(buf) -> loads hide under MFMA;
// ONE __syncthreads (vmcnt(0)+barrier) per K-tile.
// C/D frag map: col=lane&15, row=(lane>>4)*4+reg (round-3/4-proven).
// ---------------------------------------------------------------------------
template<bool OBF>
__global__ __launch_bounds__(512, 2) void gemm256(const uint16_t* __restrict__ A,
                                                  const uint16_t* __restrict__ W,
                                                  void* __restrict__ Cout,
                                                  int Nd, int K) {
  __shared__ uint16_t As[2][256 * 32];
  __shared__ uint16_t Bs[2][256 * 32];
  const int tid = threadIdx.x;
  const int l = tid & 63, w = tid >> 6;          // lane, wave 0..7
  const int wm = w >> 2, wn = w & 3;             // wave grid 2x4
  const int m0 = blockIdx.x * 256, n0 = blockIdx.y * 256;
  const int fr = l & 15, fk = (l >> 4) * 8;
  // per-thread staging source (round r adds r*128*K; wave chunk = w*16 rows)
  const uint16_t* aP = A + (size_t)(m0 + w * 16 + (l >> 2)) * K + (l & 3) * 8;
  const uint16_t* wP = W + (size_t)(n0 + w * 16 + (l >> 2)) * K + (l & 3) * 8;

  f32x4 acc[8][4];
#pragma unroll
  for (int mi = 0; mi < 8; ++mi)
#pragma unroll
    for (int nj = 0; nj < 4; ++nj) {
      f32x4 z = {0.f, 0.f, 0.f, 0.f};
      acc[mi][nj] = z;
    }

#define STAGE256(T, BUF)                                                     \
  {                                                                          \
    const size_t k0_ = (size_t)(T) * 32;                                     \
    uint16_t* as_ = &As[BUF][w * 512];                                       \
    uint16_t* bs_ = &Bs[BUF][w * 512];                                       \
    gload16(aP + k0_, as_);                                                  \
    gload16(aP + (size_t)128 * K + k0_, as_ + 4096);                         \
    gload16(wP + k0_, bs_);                                                  \
    gload16(wP + (size_t)128 * K + k0_, bs_ + 4096);                         \
  }

  const int NT = K / 32;
  STAGE256(0, 0);
  __syncthreads();                        // buf0 ready
  for (int t = 0; t < NT; ++t) {
    const int cur = t & 1;
    if (t + 1 < NT) STAGE256(t + 1, cur ^ 1);   // issue next-tile loads first
    s16x8 af[8], bf4[4];
    const uint16_t* Ab = &As[cur][(wm * 128 + fr) * 32 + fk];
    const uint16_t* Bp = &Bs[cur][(wn * 64 + fr) * 32 + fk];
#pragma unroll
    for (int mi = 0; mi < 8; ++mi) af[mi] = *(const s16x8*)(Ab + mi * 512);
#pragma unroll
    for (int nj = 0; nj < 4; ++nj) bf4[nj] = *(const s16x8*)(Bp + nj * 512);
#pragma unroll
    for (int mi = 0; mi < 8; ++mi)
#pragma unroll
      for (int nj = 0; nj < 4; ++nj)
        acc[mi][nj] = __builtin_amdgcn_mfma_f32_16x16x32_bf16(af[mi], bf4[nj],
                                                              acc[mi][nj], 0, 0, 0);
    __syncthreads();                      // vmcnt(0): t+1 landed; buf[cur] free
  }
#undef STAGE256

  const int r0 = m0 + wm * 128 + (l >> 4) * 4;
  const int c0 = n0 + wn * 64 + fr;
#pragma unroll
  for (int mi = 0; mi < 8; ++mi)
#pragma unroll
    for (int nj = 0; nj < 4; ++nj)
#pragma unroll
      for (int p = 0; p < 4; ++p) {
        const int row = r0 + mi * 16 + p;
        const int col = c0 + nj * 16;
        const float val = acc[mi][nj][p];
        if (OBF) ((uint16_t*)Cout)[(size_t)row * Nd + col] = f2b(val);
        else     ((float*)Cout)[(size_t)row * Nd + col]    = val;
      }
}

// ---------------------------------------------------------------------------
// RoPE on fused bf16 qk rows (stride QKS) in place; q scaled by 1/16.
// ---------------------------------------------------------------------------
__global__ void rope_kernel(uint16_t* __restrict__ qk) {
  const int idx = blockIdx.x * 256 + threadIdx.x;   // < B*N*H*128
  const int i = idx & 127;
  const int h = (idx >> 7) & 3;
  const int n = (idx >> 9) & (Nn - 1);
  const int b = idx >> 21;
  const size_t base = ((size_t)(b * Nn + n)) * QKS + h * DK;
  const float invf = (float)exp((double)i * -0.071955784156063938);  // 1e4^(-i/128)
  const float theta = (float)n * invf;
  float sn, cs;
  sincosf(theta, &sn, &cs);
  float x1 = b2f(qk[base + i]), x2 = b2f(qk[base + 128 + i]);
  qk[base + i]       = f2b((x1 * cs - x2 * sn) * 0.0625f);
  qk[base + 128 + i] = f2b((x2 * cs + x1 * sn) * 0.0625f);
  x1 = b2f(qk[base + 1024 + i]); x2 = b2f(qk[base + 1024 + 128 + i]);
  qk[base + 1024 + i]       = f2b(x1 * cs - x2 * sn);
  qk[base + 1024 + 128 + i] = f2b(x2 * cs + x1 * sn);
}

// ---------------------------------------------------------------------------
// Intra-chunk attention: attn fp32 [bh][c][i][j]. q,k strides = QKS.
// ---------------------------------------------------------------------------
__global__ __launch_bounds__(256) void attn_kernel(const uint16_t* __restrict__ q,
                                                   const uint16_t* __restrict__ k,
                                                   float* __restrict__ attn) {
  const int c = blockIdx.x & 63;
  const int h = (blockIdx.x >> 6) & 3;
  const int b = blockIdx.x >> 8;
  const int tid = threadIdx.x;
  __shared__ float qs[64][68];
  __shared__ float ks[64][68];
  const int i_  = tid >> 2;
  const int jb  = tid & 3;
  const int lr  = tid >> 2;
  const int lc0 = (tid & 3) * 16;
  float acc[16] = {};
  const uint16_t* qsrc = q + ((size_t)(b * Nn + c * CH + lr)) * QKS + h * DK + lc0;
  const uint16_t* ksrc = k + ((size_t)(b * Nn + c * CH + lr)) * QKS + h * DK + lc0;
  for (int dt = 0; dt < 4; ++dt) {
    __syncthreads();
#pragma unroll
    for (int u = 0; u < 2; ++u) {
      uint4 tq = *(const uint4*)(qsrc + dt * 64 + u * 8);
      uint4 tk = *(const uint4*)(ksrc + dt * 64 + u * 8);
      const int cbase = lc0 + u * 8;
      qs[lr][cbase+0] = b2f((uint16_t)tq.x); qs[lr][cbase+1] = b2f((uint16_t)(tq.x>>16));
      qs[lr][cbase+2] = b2f((uint16_t)tq.y); qs[lr][cbase+3] = b2f((uint16_t)(tq.y>>16));
      qs[lr][cbase+4] = b2f((uint16_t)tq.z); qs[lr][cbase+5] = b2f((uint16_t)(tq.z>>16));
      qs[lr][cbase+6] = b2f((uint16_t)tq.w); qs[lr][cbase+7] = b2f((uint16_t)(tq.w>>16));
      ks[lr][cbase+0] = b2f((uint16_t)tk.x); ks[lr][cbase+1] = b2f((uint16_t)(tk.x>>16));
      ks[lr][cbase+2] = b2f((uint16_t)tk.y); ks[lr][cbase+3] = b2f((uint16_t)(tk.y>>16));
      ks[lr][cbase+4] = b2f((uint16_t)tk.z); ks[lr][cbase+5] = b2f((uint16_t)(tk.z>>16));
      ks[lr][cbase+6] = b2f((uint16_t)tk.w); ks[lr][cbase+7] = b2f((uint16_t)(tk.w>>16));
    }
    __syncthreads();
    float4 qr[16];
#pragma unroll
    for (int d4 = 0; d4 < 16; ++d4) qr[d4] = *(const float4*)&qs[i_][d4 * 4];
#pragma unroll
    for (int jj = 0; jj < 16; ++jj) {
      const int j = jb + jj * 4;
      float s = 0.f;
#pragma unroll
      for (int d4 = 0; d4 < 16; ++d4) {
        float4 kk4 = *(const float4*)&ks[j][d4 * 4];
        s = fmaf(qr[d4].x, kk4.x, s); s = fmaf(qr[d4].y, kk4.y, s);
        s = fmaf(qr[d4].z, kk4.z, s); s = fmaf(qr[d4].w, kk4.w, s);
      }
      acc[jj] += s;
    }
  }
  const float gamma = 1.f - exp2f(-5.f - (float)h);
  const float l2g = log2f(gamma);
  float* arow = attn + ((((size_t)b * Hh + h) * NC + c) * CH + i_) * CH;
#pragma unroll
  for (int jj = 0; jj < 16; ++jj) {
    const int j = jb + jj * 4;
    arow[j] = (i_ >= j) ? acc[jj] * exp2f((float)(i_ - j) * l2g) : 0.f;
  }
}

// ---------------------------------------------------------------------------
// Kernel A: U_c^T[w,d] = sum_j v[j,w] * (gamma^(63-j) k[j,d])  (k stride QKS)
// ---------------------------------------------------------------------------
__global__ __launch_bounds__(256) void chunk_outer(const uint16_t* __restrict__ k,
                                                   const uint16_t* __restrict__ v,
                                                   uint16_t* __restrict__ U, int p) {
  const int c  = blockIdx.x & 63;
  const int bh = blockIdx.x >> 6;
  const int b = bh >> 2, h = bh & 3;
  const int tid = threadIdx.x;
  __shared__ uint16_t kT[256][72];   // [d][j] rows 144B (16B-aligned)
  __shared__ uint16_t vT[128][72];   // [w][j]
  const float l2g = log2f(1.f - exp2f(-5.f - (float)h));
  const int n0 = c * CH;
  {
    const int j = tid >> 2;
    const float gs = exp2f((float)(63 - j) * l2g);   // gamma^(63-j)
    const int dbase = (tid & 3) * 64;
    const uint16_t* src = k + ((size_t)(b * Nn + n0 + j)) * QKS + h * DK + dbase;
#pragma unroll
    for (int u = 0; u < 8; ++u) {
      uint4 t4 = *(const uint4*)(src + u * 8);
      const int d0 = dbase + u * 8;
      uint32_t wv_[4] = {t4.x, t4.y, t4.z, t4.w};
#pragma unroll
      for (int e = 0; e < 4; ++e) {
        kT[d0 + 2*e    ][j] = f2b(b2f((uint16_t)wv_[e]) * gs);
        kT[d0 + 2*e + 1][j] = f2b(b2f((uint16_t)(wv_[e] >> 16)) * gs);
      }
    }
    const int wbase = (tid & 3) * 32;
    const uint16_t* vsrc = v + ((size_t)(b * Nn + n0 + j)) * DM + h * DV + p * 128 + wbase;
#pragma unroll
    for (int u = 0; u < 4; ++u) {
      uint4 t4 = *(const uint4*)(vsrc + u * 8);
      const int w0 = wbase + u * 8;
      uint32_t wv_[4] = {t4.x, t4.y, t4.z, t4.w};
#pragma unroll
      for (int e = 0; e < 4; ++e) {
        vT[w0 + 2*e    ][j] = (uint16_t)wv_[e];
        vT[w0 + 2*e + 1][j] = (uint16_t)(wv_[e] >> 16);
      }
    }
  }
  __syncthreads();
  const int l = tid & 63, w = tid >> 6;
  const int wrow = (w >> 1) * 64;     // w' base (M)
  const int wcol = (w & 1) * 128;     // d  base (N)
  const int fr = l & 15, fk = (l >> 4) * 8;
  f32x4 acc[4][8];
#pragma unroll
  for (int mi = 0; mi < 4; ++mi)
#pragma unroll
    for (int nj = 0; nj < 8; ++nj) {
      f32x4 z = {0.f, 0.f, 0.f, 0.f};
      acc[mi][nj] = z;
    }
#pragma unroll
  for (int ks = 0; ks < 2; ++ks) {
    s16x8 af[4], bfr[8];
#pragma unroll
    for (int mi = 0; mi < 4; ++mi)
      af[mi] = *(const s16x8*)&vT[wrow + mi * 16 + fr][ks * 32 + fk];
#pragma unroll
    for (int nj = 0; nj < 8; ++nj)
      bfr[nj] = *(const s16x8*)&kT[wcol + nj * 16 + fr][ks * 32 + fk];
#pragma unroll
    for (int mi = 0; mi < 4; ++mi)
#pragma unroll
      for (int nj = 0; nj < 8; ++nj)
        acc[mi][nj] = __builtin_amdgcn_mfma_f32_16x16x32_bf16(af[mi], bfr[nj],
                                                              acc[mi][nj], 0, 0, 0);
  }
  uint16_t* Ub = U + (size_t)bh * 2097152 + (size_t)c * 32768;
  const int rbase = (l >> 4) * 4;
#pragma unroll
  for (int mi = 0; mi < 4; ++mi)
#pragma unroll
    for (int nj = 0; nj < 8; ++nj)
#pragma unroll
      for (int pp = 0; pp < 4; ++pp) {
        const int wq = wrow + mi * 16 + rbase + pp;
        const int d  = wcol + nj * 16 + fr;
        Ub[(size_t)wq * 256 + d] = f2b(acc[mi][nj][pp]);
      }
}

// ---------------------------------------------------------------------------
// Kernel B: in-place state scan over chunks (slot c -> S_c, bf16 snapshots).
// ---------------------------------------------------------------------------
__global__ __launch_bounds__(256) void state_scan(uint16_t* __restrict__ U) {
  const int gid = blockIdx.x * 256 + threadIdx.x;   // < 8*32768 = 262144
  const int bh = gid >> 15;
  const int e  = gid & 32767;
  const int h  = bh & 3;
  const float l2g = log2f(1.f - exp2f(-5.f - (float)h));
  const float gC = exp2f(64.f * l2g);
  uint16_t* p = U + (size_t)bh * 2097152 + e;
  float S = 0.f;
#pragma unroll 4
  for (int c = 0; c < 64; ++c) {
    uint16_t* slot = p + (size_t)c * 32768;
    const float u = b2f(*slot);
    *slot = f2b(S);
    S = gC * S + u;
  }
}

// ---------------------------------------------------------------------------
// Kernel C: o[i,w] = (attn_c @ v_c)[i,w] + gamma^(i+1)*(q_c @ S_c)[i,w]
// (q stride QKS)
// ---------------------------------------------------------------------------
__global__ __launch_bounds__(256) void scan_out(const uint16_t* __restrict__ q,
                                                const uint16_t* __restrict__ v,
                                                const float* __restrict__ attn,
                                                const uint16_t* __restrict__ U,
                                                float* __restrict__ o, int p) {
  const int c  = blockIdx.x & 63;
  const int bh = blockIdx.x >> 6;
  const int b = bh >> 2, h = bh & 3;
  const int tid = threadIdx.x;
  __shared__ uint16_t vT[128][72];
  __shared__ float gp[65];
  const float l2g = log2f(1.f - exp2f(-5.f - (float)h));
  if (tid < 65) gp[tid] = exp2f((float)tid * l2g);
  const int n0 = c * CH;
  {
    const int j = tid >> 2;
    const int wbase = (tid & 3) * 32;
    const uint16_t* vsrc = v + ((size_t)(b * Nn + n0 + j)) * DM + h * DV + p * 128 + wbase;
#pragma unroll
    for (int u = 0; u < 4; ++u) {
      uint4 t4 = *(const uint4*)(vsrc + u * 8);
      const int w0 = wbase + u * 8;
      uint32_t wv_[4] = {t4.x, t4.y, t4.z, t4.w};
#pragma unroll
      for (int e = 0; e < 4; ++e) {
        vT[w0 + 2*e    ][j] = (uint16_t)wv_[e];
        vT[w0 + 2*e + 1][j] = (uint16_t)(wv_[e] >> 16);
      }
    }
  }
  __syncthreads();
  const int l = tid & 63, wv = tid >> 6;
  const int wcol = wv * 32;
  const int fr = l & 15, fk = (l >> 4) * 8;
  f32x4 aQS[4][2], aPV[4][2];
#pragma unroll
  for (int mi = 0; mi < 4; ++mi)
#pragma unroll
    for (int nj = 0; nj < 2; ++nj) {
      f32x4 z = {0.f, 0.f, 0.f, 0.f};
      aQS[mi][nj] = z; aPV[mi][nj] = z;
    }
  const uint16_t* qbase = q + ((size_t)(b * Nn + n0)) * QKS + h * DK;
  const uint16_t* Ub = U + (size_t)bh * 2097152 + (size_t)c * 32768;
  // q @ S  (K = 256)
#pragma unroll
  for (int ks = 0; ks < 8; ++ks) {
    s16x8 qf[4], sf[2];
#pragma unroll
    for (int mi = 0; mi < 4; ++mi)
      qf[mi] = *(const s16x8*)(qbase + (size_t)(mi * 16 + fr) * QKS + ks * 32 + fk);
#pragma unroll
    for (int nj = 0; nj < 2; ++nj)
      sf[nj] = *(const s16x8*)(Ub + (size_t)(wcol + nj * 16 + fr) * 256 + ks * 32 + fk);
#pragma unroll
    for (int mi = 0; mi < 4; ++mi)
#pragma unroll
      for (int nj = 0; nj < 2; ++nj)
        aQS[mi][nj] = __builtin_amdgcn_mfma_f32_16x16x32_bf16(qf[mi], sf[nj],
                                                              aQS[mi][nj], 0, 0, 0);
  }
  // attn @ v  (K = 64)
  const float* ab = attn + (((size_t)bh * 64 + c) * 64) * 64;
#pragma unroll
  for (int ks = 0; ks < 2; ++ks) {
    s16x8 af[4], vf[2];
#pragma unroll
    for (int mi = 0; mi < 4; ++mi) {
      const float* ar = ab + (size_t)(mi * 16 + fr) * 64 + ks * 32 + fk;
      float4 a0 = *(const float4*)ar;
      float4 a1 = *(const float4*)(ar + 4);
      s16x8 t;
      t[0] = (short)f2b(a0.x); t[1] = (short)f2b(a0.y);
      t[2] = (short)f2b(a0.z); t[3] = (short)f2b(a0.w);
      t[4] = (short)f2b(a1.x); t[5] = (short)f2b(a1.y);
      t[6] = (short)f2b(a1.z); t[7] = (short)f2b(a1.w);
      af[mi] = t;
    }
#pragma unroll
    for (int nj = 0; nj < 2; ++nj)
      vf[nj] = *(const s16x8*)&vT[wcol + nj * 16 + fr][ks * 32 + fk];
#pragma unroll
    for (int mi = 0; mi < 4; ++mi)
#pragma unroll
      for (int nj = 0; nj < 2; ++nj)
        aPV[mi][nj] = __builtin_amdgcn_mfma_f32_16x16x32_bf16(af[mi], vf[nj],
                                                              aPV[mi][nj], 0, 0, 0);
  }
  const int rbase = (l >> 4) * 4;
#pragma unroll
  for (int mi = 0; mi < 4; ++mi)
#pragma unroll
    for (int nj = 0; nj < 2; ++nj)
#pragma unroll
      for (int pp = 0; pp < 4; ++pp) {
        const int i = mi * 16 + rbase + pp;
        const int wc_ = wcol + nj * 16 + fr;
        const float val = aPV[mi][nj][pp] + gp[i + 1] * aQS[mi][nj][pp];
        o[((size_t)(b * Nn + n0 + i)) * DM + h * DV + p * 128 + wc_] = val;
      }
}

// ---------------------------------------------------------------------------
// GroupNorm over DV per (b,n,h) + SiLU gate, in place into bf16 g.
// ---------------------------------------------------------------------------
__global__ __launch_bounds__(256) void gn_gate(const float* __restrict__ o,
                                               uint16_t* __restrict__ g,
                                               const float* __restrict__ gw) {
  const int bn = blockIdx.x;
  const int tid = threadIdx.x;
  const int h = tid >> 6;
  const int lane = tid & 63;
  const size_t base = (size_t)bn * DM + h * DV + lane * 8;
  float4 o0 = *(const float4*)&o[base];
  float4 o1 = *(const float4*)&o[base + 4];
  float ss = o0.x*o0.x + o0.y*o0.y + o0.z*o0.z + o0.w*o0.w
           + o1.x*o1.x + o1.y*o1.y + o1.z*o1.z + o1.w*o1.w;
#pragma unroll
  for (int m = 1; m < 64; m <<= 1) ss += __shfl_xor(ss, m, 64);
  const float r = rsqrtf(ss * (1.f / 512.f) + 1e-5f);
  uint4 gv = *(const uint4*)&g[base];
  float gf[8] = { b2f((uint16_t)gv.x), b2f((uint16_t)(gv.x >> 16)),
                  b2f((uint16_t)gv.y), b2f((uint16_t)(gv.y >> 16)),
                  b2f((uint16_t)gv.z), b2f((uint16_t)(gv.z >> 16)),
                  b2f((uint16_t)gv.w), b2f((uint16_t)(gv.w >> 16)) };
  float ov[8] = { o0.x, o0.y, o0.z, o0.w, o1.x, o1.y, o1.z, o1.w };
  const float* gwp = gw + lane * 8;
  uint16_t res[8];
#pragma unroll
  for (int e = 0; e < 8; ++e) {
    float sil = gf[e] / (1.f + expf(-gf[e]));
    res[e] = f2b(ov[e] * r * gwp[e] * sil);
  }
  uint4 outv;
  outv.x = (uint32_t)res[0] | ((uint32_t)res[1] << 16);
  outv.y = (uint32_t)res[2] | ((uint32_t)res[3] << 16);
  outv.z = (uint32_t)res[4] | ((uint32_t)res[5] << 16);
  outv.w = (uint32_t)res[6] | ((uint32_t)res[7] << 16);
  *(uint4*)&g[base] = outv;
}

// ---------------------------------------------------------------------------
// ws layout (MB), peak 136 (proven size):
//   [  0, 32)  qkb (fused q|k, stride 2048)   -> phase 3: xb2 overlays
//   [ 32, 64)  vb                              -> phase 3: gb overlays
//   [ 64, 72)  attn (fp32)
//   [ 72, 80)  wqkb (stacked Wq;Wk)  [80,88) wvb  [88,96) wgb  [96,104) wob
//   [104,136)  xb (phase 1)  ->  U/S (scan passes, 32 MiB)
// o (fp32) lives in d_out until gn_gate; final GEMM overwrites d_out.
// Every region fully rewritten before read each launch -> graph-replay safe.
// ---------------------------------------------------------------------------
extern "C" void kernel_launch(void* const* d_in, const int* in_sizes, int n_in,
                              void* d_out, int out_size, void* d_ws, size_t ws_size,
                              hipStream_t stream) {
  const float* x  = (const float*)d_in[0];
  const float* Wq = (const float*)d_in[1];
  const float* Wk = (const float*)d_in[2];
  const float* Wv = (const float*)d_in[3];
  const float* Wg = (const float*)d_in[4];
  const float* Wo = (const float*)d_in[5];
  const float* gw = (const float*)d_in[6];

  char* base = (char*)d_ws;
  uint16_t* qkb  = (uint16_t*)(base);
  uint16_t* vb   = (uint16_t*)(base + ((size_t)32 << 20));
  float*    attn = (float*)   (base + ((size_t)64 << 20));
  uint16_t* wqkb = (uint16_t*)(base + ((size_t)72 << 20));
  uint16_t* wvb  = (uint16_t*)(base + ((size_t)80 << 20));
  uint16_t* wgb  = (uint16_t*)(base + ((size_t)88 << 20));
  uint16_t* wob  = (uint16_t*)(base + ((size_t)96 << 20));
  uint16_t* xb   = (uint16_t*)(base + ((size_t)104 << 20));
  uint16_t* Ub   = xb;                     // U/S overlays xb during scan
  uint16_t* xb2  = qkb;                    // phase-3 x (overlays dead qkb)
  uint16_t* gb   = vb;                     // phase-3 g (overlays dead vb)
  uint16_t* qb   = qkb;                    // q = cols 0-1023
  uint16_t* kb   = qkb + 1024;             // k = cols 1024-2047
  float*    o    = (float*)d_out;          // scratch until gn_gate

  dim3 blk(256), blkG(512);
  conv_f2b<<<dim3(8192), blk, 0, stream>>>(x,  xb,  M * DM / 8);
  conv_f2b<<<dim3(1024), blk, 0, stream>>>(Wq, wqkb, 1024 * DM / 8);
  conv_f2b<<<dim3(1024), blk, 0, stream>>>(Wk, wqkb + 1024 * DM, 1024 * DM / 8);
  conv_f2b<<<dim3(2048), blk, 0, stream>>>(Wv, wvb, DM * DM / 8);
  conv_f2b<<<dim3(2048), blk, 0, stream>>>(Wg, wgb, DM * DM / 8);
  conv_f2b<<<dim3(2048), blk, 0, stream>>>(Wo, wob, DM * DM / 8);
  gemm256<true><<<dim3(M/256, DM/256), blkG, 0, stream>>>(xb, wqkb, qkb, DM, DM);
  gemm256<true><<<dim3(M/256, DM/256), blkG, 0, stream>>>(xb, wvb,  vb,  DM, DM);
  rope_kernel<<<dim3((Bb*Nn*Hh*128)/256), blk, 0, stream>>>(qkb);
  attn_kernel<<<dim3(Bb*Hh*NC), blk, 0, stream>>>(qb, kb, attn);
  // xb dead from here; U/S overlays it
  for (int p = 0; p < 4; ++p) {
    chunk_outer<<<dim3(Bb*Hh*NC),  blk, 0, stream>>>(kb, vb, Ub, p);
    state_scan<<<dim3(1024),       blk, 0, stream>>>(Ub);
    scan_out<<<dim3(Bb*Hh*NC),     blk, 0, stream>>>(qb, vb, attn, Ub, o, p);
  }
  // phase 3: qkb/vb dead
  conv_f2b<<<dim3(8192), blk, 0, stream>>>(x, xb2, M * DM / 8);
  gemm256<true><<<dim3(M/256, DM/256), blkG, 0, stream>>>(xb2, wgb, gb, DM, DM);
  gn_gate<<<dim3(M), blk, 0, stream>>>(o, gb, gw);
  gemm256<false><<<dim3(M/256, DM/256), blkG, 0, stream>>>(gb, wob, (float*)d_out, DM, DM);
}

// Round 7
// 623.220 us; speedup vs baseline: 7.8708x; 1.0834x over previous
//
#include <hip/hip_runtime.h>
#include <hip/hip_bf16.h>
#include <stdint.h>

// Problem constants (MultiScaleRetention: B=2, N=4096, D_MODEL=2048, H=4)
constexpr int Bb   = 2;
constexpr int Nn   = 4096;
constexpr int DM   = 2048;
constexpr int Hh   = 4;
constexpr int DK   = 256;    // KEY_DIM / H
constexpr int DV   = 512;    // D_MODEL / H
constexpr int QKS  = 2048;   // fused q|k row stride (q cols 0-1023, k cols 1024-2047)
constexpr int CH   = 64;     // chunk
constexpr int NC   = Nn / CH;   // 64 chunks
constexpr int M    = Bb * Nn;   // 8192 rows

typedef __attribute__((ext_vector_type(8))) short s16x8;   // 8 bf16 (4 VGPRs)
typedef __attribute__((ext_vector_type(4))) float f32x4;

__device__ __forceinline__ float b2f(uint16_t h) {
  return __uint_as_float(((uint32_t)h) << 16);
}
__device__ __forceinline__ uint16_t f2b(float f) {   // RNE, finite inputs
  uint32_t u = __float_as_uint(f);
  return (uint16_t)((u + 0x7fffu + ((u >> 16) & 1u)) >> 16);
}

// async global->LDS, 16B per lane; LDS dest = wave-uniform base + lane*16
__device__ __forceinline__ void gload16(const void* g, void* l) {
  __builtin_amdgcn_global_load_lds(
      (const __attribute__((address_space(1))) void*)g,
      (__attribute__((address_space(3))) void*)l, 16, 0, 0);
}

// ---------------------------------------------------------------------------
// fp32 -> bf16 bulk convert, 8 elems/thread
// ---------------------------------------------------------------------------
__global__ __launch_bounds__(256) void conv_f2b(const float* __restrict__ s,
                                                uint16_t* __restrict__ d, int n8) {
  int i = blockIdx.x * 256 + threadIdx.x;
  if (i >= n8) return;
  const float4* sp = (const float4*)s;
  float4 a = sp[2 * i], b = sp[2 * i + 1];
  uint4 o;
  o.x = (uint32_t)f2b(a.x) | ((uint32_t)f2b(a.y) << 16);
  o.y = (uint32_t)f2b(a.z) | ((uint32_t)f2b(a.w) << 16);
  o.z = (uint32_t)f2b(b.x) | ((uint32_t)f2b(b.y) << 16);
  o.w = (uint32_t)f2b(b.z) | ((uint32_t)f2b(b.w) << 16);
  ((uint4*)d)[i] = o;
}

// ---------------------------------------------------------------------------
// 256x256 bf16 MFMA GEMM, 2-phase double-buffered (unchanged, round-6-proven)
// ---------------------------------------------------------------------------
template<bool OBF>
__global__ __launch_bounds__(512, 2) void gemm256(const uint16_t* __restrict__ A,
                                                  const uint16_t* __restrict__ W,
                                                  void* __restrict__ Cout,
                                                  int Nd, int K) {
  __shared__ uint16_t As[2][256 * 32];
  __shared__ uint16_t Bs[2][256 * 32];
  const int tid = threadIdx.x;
  const int l = tid & 63, w = tid >> 6;          // lane, wave 0..7
  const int wm = w >> 2, wn = w & 3;             // wave grid 2x4
  const int m0 = blockIdx.x * 256, n0 = blockIdx.y * 256;
  const int fr = l & 15, fk = (l >> 4) * 8;
  const uint16_t* aP = A + (size_t)(m0 + w * 16 + (l >> 2)) * K + (l & 3) * 8;
  const uint16_t* wP = W + (size_t)(n0 + w * 16 + (l >> 2)) * K + (l & 3) * 8;

  f32x4 acc[8][4];
#pragma unroll
  for (int mi = 0; mi < 8; ++mi)
#pragma unroll
    for (int nj = 0; nj < 4; ++nj) {
      f32x4 z = {0.f, 0.f, 0.f, 0.f};
      acc[mi][nj] = z;
    }

#define STAGE256(T, BUF)                                                     \
  {                                                                          \
    const size_t k0_ = (size_t)(T) * 32;                                     \
    uint16_t* as_ = &As[BUF][w * 512];                                       \
    uint16_t* bs_ = &Bs[BUF][w * 512];                                       \
    gload16(aP + k0_, as_);                                                  \
    gload16(aP + (size_t)128 * K + k0_, as_ + 4096);                         \
    gload16(wP + k0_, bs_);                                                  \
    gload16(wP + (size_t)128 * K + k0_, bs_ + 4096);                         \
  }

  const int NT = K / 32;
  STAGE256(0, 0);
  __syncthreads();
  for (int t = 0; t < NT; ++t) {
    const int cur = t & 1;
    if (t + 1 < NT) STAGE256(t + 1, cur ^ 1);
    s16x8 af[8], bf4[4];
    const uint16_t* Ab = &As[cur][(wm * 128 + fr) * 32 + fk];
    const uint16_t* Bp = &Bs[cur][(wn * 64 + fr) * 32 + fk];
#pragma unroll
    for (int mi = 0; mi < 8; ++mi) af[mi] = *(const s16x8*)(Ab + mi * 512);
#pragma unroll
    for (int nj = 0; nj < 4; ++nj) bf4[nj] = *(const s16x8*)(Bp + nj * 512);
#pragma unroll
    for (int mi = 0; mi < 8; ++mi)
#pragma unroll
      for (int nj = 0; nj < 4; ++nj)
        acc[mi][nj] = __builtin_amdgcn_mfma_f32_16x16x32_bf16(af[mi], bf4[nj],
                                                              acc[mi][nj], 0, 0, 0);
    __syncthreads();
  }
#undef STAGE256

  const int r0 = m0 + wm * 128 + (l >> 4) * 4;
  const int c0 = n0 + wn * 64 + fr;
#pragma unroll
  for (int mi = 0; mi < 8; ++mi)
#pragma unroll
    for (int nj = 0; nj < 4; ++nj)
#pragma unroll
      for (int p = 0; p < 4; ++p) {
        const int row = r0 + mi * 16 + p;
        const int col = c0 + nj * 16;
        const float val = acc[mi][nj][p];
        if (OBF) ((uint16_t*)Cout)[(size_t)row * Nd + col] = f2b(val);
        else     ((float*)Cout)[(size_t)row * Nd + col]    = val;
      }
}

// ---------------------------------------------------------------------------
// RoPE on fused bf16 qk rows (stride QKS) in place; q scaled by 1/16.
// ---------------------------------------------------------------------------
__global__ void rope_kernel(uint16_t* __restrict__ qk) {
  const int idx = blockIdx.x * 256 + threadIdx.x;   // < B*N*H*128
  const int i = idx & 127;
  const int h = (idx >> 7) & 3;
  const int n = (idx >> 9) & (Nn - 1);
  const int b = idx >> 21;
  const size_t base = ((size_t)(b * Nn + n)) * QKS + h * DK;
  const float invf = (float)exp((double)i * -0.071955784156063938);  // 1e4^(-i/128)
  const float theta = (float)n * invf;
  float sn, cs;
  sincosf(theta, &sn, &cs);
  float x1 = b2f(qk[base + i]), x2 = b2f(qk[base + 128 + i]);
  qk[base + i]       = f2b((x1 * cs - x2 * sn) * 0.0625f);
  qk[base + 128 + i] = f2b((x2 * cs + x1 * sn) * 0.0625f);
  x1 = b2f(qk[base + 1024 + i]); x2 = b2f(qk[base + 1024 + 128 + i]);
  qk[base + 1024 + i]       = f2b(x1 * cs - x2 * sn);
  qk[base + 1024 + 128 + i] = f2b(x2 * cs + x1 * sn);
}

// ---------------------------------------------------------------------------
// v transpose: vt[bh][w][n] = v[b][n][h*DV + w].  64x64 LDS tiles, both sides
// coalesced. grid = bh(8) x wt(8) x nt(64) = 4096 blocks.
// ---------------------------------------------------------------------------
__global__ __launch_bounds__(256) void transpose_v(const uint16_t* __restrict__ v,
                                                   uint16_t* __restrict__ vt) {
  const int nt = blockIdx.x & 63;
  const int wt = (blockIdx.x >> 6) & 7;
  const int bh = blockIdx.x >> 9;
  const int b = bh >> 2, h = bh & 3;
  __shared__ uint16_t t[64][72];
  const int lr = threadIdx.x >> 2, lc = (threadIdx.x & 3) * 16;
  const uint16_t* src = v + ((size_t)(b * Nn + nt * 64 + lr)) * DM + h * DV + wt * 64 + lc;
  *(uint4*)&t[lr][lc]     = *(const uint4*)src;
  *(uint4*)&t[lr][lc + 8] = *(const uint4*)(src + 8);
  __syncthreads();
  uint16_t out[16];
#pragma unroll
  for (int e = 0; e < 16; ++e) out[e] = t[lc + e][lr];
  uint16_t* dst = vt + ((size_t)bh * 512 + wt * 64 + lr) * 4096 + nt * 64 + lc;
  *(uint4*)dst       = *(uint4*)&out[0];
  *(uint4*)(dst + 8) = *(uint4*)&out[8];
}

// ---------------------------------------------------------------------------
// k transpose + gamma-scale: kt[bh][d][n] = gamma_h^(63-(n&63)) * k[b][n][d]
// (k = qk cols 1024+h*DK). grid = bh(8) x dt(4) x nt(64) = 2048 blocks.
// ---------------------------------------------------------------------------
__global__ __launch_bounds__(256) void transpose_k(const uint16_t* __restrict__ qk,
                                                   uint16_t* __restrict__ kt) {
  const int nt = blockIdx.x & 63;
  const int dt = (blockIdx.x >> 6) & 3;
  const int bh = blockIdx.x >> 8;
  const int b = bh >> 2, h = bh & 3;
  __shared__ uint16_t t[64][72];
  const int lr = threadIdx.x >> 2, lc = (threadIdx.x & 3) * 16;
  const uint16_t* src = qk + ((size_t)(b * Nn + nt * 64 + lr)) * QKS + 1024 + h * DK + dt * 64 + lc;
  *(uint4*)&t[lr][lc]     = *(const uint4*)src;
  *(uint4*)&t[lr][lc + 8] = *(const uint4*)(src + 8);
  __syncthreads();
  const float l2g = log2f(1.f - exp2f(-5.f - (float)h));
  uint16_t out[16];
#pragma unroll
  for (int e = 0; e < 16; ++e)
    out[e] = f2b(b2f(t[lc + e][lr]) * exp2f((float)(63 - (lc + e)) * l2g));
  uint16_t* dst = kt + ((size_t)bh * 256 + dt * 64 + lr) * 4096 + nt * 64 + lc;
  *(uint4*)dst       = *(uint4*)&out[0];
  *(uint4*)(dst + 8) = *(uint4*)&out[8];
}

// ---------------------------------------------------------------------------
// Intra-chunk attention via MFMA: attn[bh][c][i][j] (bf16) =
//   (i>=j) ? (q_i . k_j) * gamma^(i-j) : 0.   q pre-scaled (rope).
// grid = 512 blocks (bh,c), 4 waves; wave w = row block w*16. All fragments
// read directly from global (chunk q/k = 64KB, L2-resident).
// ---------------------------------------------------------------------------
__global__ __launch_bounds__(256) void attn_mfma(const uint16_t* __restrict__ qk,
                                                 uint16_t* __restrict__ attn) {
  const int c  = blockIdx.x & 63;
  const int bh = blockIdx.x >> 6;
  const int b = bh >> 2, h = bh & 3;
  const int tid = threadIdx.x;
  const int l = tid & 63, w = tid >> 6;
  const int fr = l & 15, fk = (l >> 4) * 8;
  const int n0 = c * CH;
  const uint16_t* qbase = qk + ((size_t)(b * Nn + n0)) * QKS + h * DK;
  const uint16_t* kbase = qbase + 1024;
  f32x4 acc[4];
#pragma unroll
  for (int nj = 0; nj < 4; ++nj) {
    f32x4 z = {0.f, 0.f, 0.f, 0.f};
    acc[nj] = z;
  }
#pragma unroll
  for (int ks = 0; ks < 8; ++ks) {
    s16x8 qf = *(const s16x8*)(qbase + (size_t)(w * 16 + fr) * QKS + ks * 32 + fk);
    s16x8 kf[4];
#pragma unroll
    for (int nj = 0; nj < 4; ++nj)
      kf[nj] = *(const s16x8*)(kbase + (size_t)(nj * 16 + fr) * QKS + ks * 32 + fk);
#pragma unroll
    for (int nj = 0; nj < 4; ++nj)
      acc[nj] = __builtin_amdgcn_mfma_f32_16x16x32_bf16(qf, kf[nj], acc[nj], 0, 0, 0);
  }
  const float l2g = log2f(1.f - exp2f(-5.f - (float)h));
  uint16_t* ab = attn + ((size_t)bh * 64 + c) * 4096;
  const int rbase = (l >> 4) * 4;
#pragma unroll
  for (int pp = 0; pp < 4; ++pp) {
    const int i = w * 16 + rbase + pp;
#pragma unroll
    for (int nj = 0; nj < 4; ++nj) {
      const int j = nj * 16 + fr;
      const float val = (i >= j) ? acc[nj][pp] * exp2f((float)(i - j) * l2g) : 0.f;
      ab[(size_t)i * 64 + j] = f2b(val);
    }
  }
}

// ---------------------------------------------------------------------------
// Kernel A: U_c^T[w,d] = sum_j vt[w,j] * kt[d,j]   (kt pre-scaled by gamma)
// All fragments direct from global (kt/vt are j-contiguous). No LDS.
// ---------------------------------------------------------------------------
__global__ __launch_bounds__(256) void chunk_outer(const uint16_t* __restrict__ kt,
                                                   const uint16_t* __restrict__ vt,
                                                   uint16_t* __restrict__ U, int p) {
  const int c  = blockIdx.x & 63;
  const int bh = blockIdx.x >> 6;
  const int tid = threadIdx.x;
  const int l = tid & 63, w = tid >> 6;
  const int wrow = (w >> 1) * 64;     // w' base (M)
  const int wcol = (w & 1) * 128;     // d  base (N)
  const int fr = l & 15, fk = (l >> 4) * 8;
  const int n0 = c * CH;
  const uint16_t* vtb = vt + ((size_t)bh * 512 + p * 128) * 4096 + n0;
  const uint16_t* ktb = kt + ((size_t)bh * 256) * 4096 + n0;
  f32x4 acc[4][8];
#pragma unroll
  for (int mi = 0; mi < 4; ++mi)
#pragma unroll
    for (int nj = 0; nj < 8; ++nj) {
      f32x4 z = {0.f, 0.f, 0.f, 0.f};
      acc[mi][nj] = z;
    }
#pragma unroll
  for (int ks = 0; ks < 2; ++ks) {
    s16x8 af[4], bf8[8];
#pragma unroll
    for (int mi = 0; mi < 4; ++mi)
      af[mi] = *(const s16x8*)(vtb + (size_t)(wrow + mi * 16 + fr) * 4096 + ks * 32 + fk);
#pragma unroll
    for (int nj = 0; nj < 8; ++nj)
      bf8[nj] = *(const s16x8*)(ktb + (size_t)(wcol + nj * 16 + fr) * 4096 + ks * 32 + fk);
#pragma unroll
    for (int mi = 0; mi < 4; ++mi)
#pragma unroll
      for (int nj = 0; nj < 8; ++nj)
        acc[mi][nj] = __builtin_amdgcn_mfma_f32_16x16x32_bf16(af[mi], bf8[nj],
                                                              acc[mi][nj], 0, 0, 0);
  }
  uint16_t* Ub = U + (size_t)bh * 2097152 + (size_t)c * 32768;
  const int rbase = (l >> 4) * 4;
#pragma unroll
  for (int mi = 0; mi < 4; ++mi)
#pragma unroll
    for (int nj = 0; nj < 8; ++nj)
#pragma unroll
      for (int pp = 0; pp < 4; ++pp) {
        const int wq = wrow + mi * 16 + rbase + pp;
        const int d  = wcol + nj * 16 + fr;
        Ub[(size_t)wq * 256 + d] = f2b(acc[mi][nj][pp]);
      }
}

// ---------------------------------------------------------------------------
// Kernel B: in-place state scan (slot c -> S_c). 8-batch load prefetch:
// 8 independent loads land under one latency window, then serial FMA chain.
// ---------------------------------------------------------------------------
__global__ __launch_bounds__(256) void state_scan(uint16_t* __restrict__ U) {
  const int gid = blockIdx.x * 256 + threadIdx.x;   // < 8*32768 = 262144
  const int bh = gid >> 15;
  const int e  = gid & 32767;
  const int h  = bh & 3;
  const float l2g = log2f(1.f - exp2f(-5.f - (float)h));
  const float gC = exp2f(64.f * l2g);
  uint16_t* p = U + (size_t)bh * 2097152 + e;
  float S = 0.f;
  for (int cb = 0; cb < 8; ++cb) {
    uint16_t* base = p + (size_t)cb * 8 * 32768;
    float u[8];
#pragma unroll
    for (int ee = 0; ee < 8; ++ee) u[ee] = b2f(base[(size_t)ee * 32768]);
#pragma unroll
    for (int ee = 0; ee < 8; ++ee) {
      base[(size_t)ee * 32768] = f2b(S);
      S = gC * S + u[ee];
    }
  }
}

// ---------------------------------------------------------------------------
// Kernel C: o[i,w] = (attn_c @ v_c)[i,w] + gamma^(i+1)*(q_c @ S_c)[i,w]
// attn bf16 + vt + U + q all direct-global fragments; no LDS, no barrier.
// o written bf16 (into d_out scratch region).
// ---------------------------------------------------------------------------
__global__ __launch_bounds__(256) void scan_out(const uint16_t* __restrict__ qk,
                                                const uint16_t* __restrict__ vt,
                                                const uint16_t* __restrict__ attn,
                                                const uint16_t* __restrict__ U,
                                                uint16_t* __restrict__ o, int p) {
  const int c  = blockIdx.x & 63;
  const int bh = blockIdx.x >> 6;
  const int b = bh >> 2, h = bh & 3;
  const int tid = threadIdx.x;
  const int l = tid & 63, wv = tid >> 6;
  const int wcol = wv * 32;                 // output col base (within pass 128)
  const int fr = l & 15, fk = (l >> 4) * 8;
  const int n0 = c * CH;
  f32x4 aQS[4][2], aPV[4][2];
#pragma unroll
  for (int mi = 0; mi < 4; ++mi)
#pragma unroll
    for (int nj = 0; nj < 2; ++nj) {
      f32x4 z = {0.f, 0.f, 0.f, 0.f};
      aQS[mi][nj] = z; aPV[mi][nj] = z;
    }
  const uint16_t* qbase = qk + ((size_t)(b * Nn + n0)) * QKS + h * DK;
  const uint16_t* Ub = U + (size_t)bh * 2097152 + (size_t)c * 32768;
  // q @ S  (K = 256)
#pragma unroll
  for (int ks = 0; ks < 8; ++ks) {
    s16x8 qf[4], sf[2];
#pragma unroll
    for (int mi = 0; mi < 4; ++mi)
      qf[mi] = *(const s16x8*)(qbase + (size_t)(mi * 16 + fr) * QKS + ks * 32 + fk);
#pragma unroll
    for (int nj = 0; nj < 2; ++nj)
      sf[nj] = *(const s16x8*)(Ub + (size_t)(wcol + nj * 16 + fr) * 256 + ks * 32 + fk);
#pragma unroll
    for (int mi = 0; mi < 4; ++mi)
#pragma unroll
      for (int nj = 0; nj < 2; ++nj)
        aQS[mi][nj] = __builtin_amdgcn_mfma_f32_16x16x32_bf16(qf[mi], sf[nj],
                                                              aQS[mi][nj], 0, 0, 0);
  }
  // attn @ v  (K = 64)
  const uint16_t* ab = attn + ((size_t)bh * 64 + c) * 4096;
  const uint16_t* vtb = vt + ((size_t)bh * 512 + p * 128) * 4096 + n0;
#pragma unroll
  for (int ks = 0; ks < 2; ++ks) {
    s16x8 af[4], vf[2];
#pragma unroll
    for (int mi = 0; mi < 4; ++mi)
      af[mi] = *(const s16x8*)(ab + (size_t)(mi * 16 + fr) * 64 + ks * 32 + fk);
#pragma unroll
    for (int nj = 0; nj < 2; ++nj)
      vf[nj] = *(const s16x8*)(vtb + (size_t)(wcol + nj * 16 + fr) * 4096 + ks * 32 + fk);
#pragma unroll
    for (int mi = 0; mi < 4; ++mi)
#pragma unroll
      for (int nj = 0; nj < 2; ++nj)
        aPV[mi][nj] = __builtin_amdgcn_mfma_f32_16x16x32_bf16(af[mi], vf[nj],
                                                              aPV[mi][nj], 0, 0, 0);
  }
  const float l2g = log2f(1.f - exp2f(-5.f - (float)h));
  const int rbase = (l >> 4) * 4;
#pragma unroll
  for (int mi = 0; mi < 4; ++mi)
#pragma unroll
    for (int pp = 0; pp < 4; ++pp) {
      const int i = mi * 16 + rbase + pp;
      const float gi = exp2f((float)(i + 1) * l2g);
#pragma unroll
      for (int nj = 0; nj < 2; ++nj) {
        const int wc_ = wcol + nj * 16 + fr;
        const float val = aPV[mi][nj][pp] + gi * aQS[mi][nj][pp];
        o[((size_t)(b * Nn + n0 + i)) * DM + h * DV + p * 128 + wc_] = f2b(val);
      }
    }
}

// ---------------------------------------------------------------------------
// GroupNorm over DV per (b,n,h) + SiLU gate (o now bf16), in place into g.
// ---------------------------------------------------------------------------
__global__ __launch_bounds__(256) void gn_gate(const uint16_t* __restrict__ o,
                                               uint16_t* __restrict__ g,
                                               const float* __restrict__ gw) {
  const int bn = blockIdx.x;
  const int tid = threadIdx.x;
  const int h = tid >> 6;
  const int lane = tid & 63;
  const size_t base = (size_t)bn * DM + h * DV + lane * 8;
  uint4 ov4 = *(const uint4*)&o[base];
  float ov[8] = { b2f((uint16_t)ov4.x), b2f((uint16_t)(ov4.x >> 16)),
                  b2f((uint16_t)ov4.y), b2f((uint16_t)(ov4.y >> 16)),
                  b2f((uint16_t)ov4.z), b2f((uint16_t)(ov4.z >> 16)),
                  b2f((uint16_t)ov4.w), b2f((uint16_t)(ov4.w >> 16)) };
  float ss = 0.f;
#pragma unroll
  for (int e = 0; e < 8; ++e) ss += ov[e] * ov[e];
#pragma unroll
  for (int m = 1; m < 64; m <<= 1) ss += __shfl_xor(ss, m, 64);
  const float r = rsqrtf(ss * (1.f / 512.f) + 1e-5f);
  uint4 gv = *(const uint4*)&g[base];
  float gf[8] = { b2f((uint16_t)gv.x), b2f((uint16_t)(gv.x >> 16)),
                  b2f((uint16_t)gv.y), b2f((uint16_t)(gv.y >> 16)),
                  b2f((uint16_t)gv.z), b2f((uint16_t)(gv.z >> 16)),
                  b2f((uint16_t)gv.w), b2f((uint16_t)(gv.w >> 16)) };
  const float* gwp = gw + lane * 8;
  uint16_t res[8];
#pragma unroll
  for (int e = 0; e < 8; ++e) {
    float sil = gf[e] / (1.f + expf(-gf[e]));
    res[e] = f2b(ov[e] * r * gwp[e] * sil);
  }
  uint4 outv;
  outv.x = (uint32_t)res[0] | ((uint32_t)res[1] << 16);
  outv.y = (uint32_t)res[2] | ((uint32_t)res[3] << 16);
  outv.z = (uint32_t)res[4] | ((uint32_t)res[5] << 16);
  outv.w = (uint32_t)res[6] | ((uint32_t)res[7] << 16);
  *(uint4*)&g[base] = outv;
}

// ---------------------------------------------------------------------------
// ws layout (MB), peak 160 (= round-2 proven size). Overlays (write-before-read
// ordered by the stream):
//   [  0, 32)  xb (phase1; dead after g-GEMM)        -> U (scan)
//   [ 32, 64)  qkb (fused q|k, stride 2048)
//   [ 64, 96)  vb (dead after transpose_v)           -> kt[64,80) attn[80,84)
//                                                       wob[84,92)
//   [ 96,128)  gb (g-GEMM out, read by gn_gate)
//   [128,160)  wqkb[128,136) wvb[136,144) wgb[144,152) (dead after GEMMs)
//                                                    -> vt[128,160)
// o (bf16) lives in d_out's first 32MB until gn_gate; final GEMM overwrites
// d_out with fp32. Every region fully written before read -> graph-replay safe.
// ---------------------------------------------------------------------------
extern "C" void kernel_launch(void* const* d_in, const int* in_sizes, int n_in,
                              void* d_out, int out_size, void* d_ws, size_t ws_size,
                              hipStream_t stream) {
  const float* x  = (const float*)d_in[0];
  const float* Wq = (const float*)d_in[1];
  const float* Wk = (const float*)d_in[2];
  const float* Wv = (const float*)d_in[3];
  const float* Wg = (const float*)d_in[4];
  const float* Wo = (const float*)d_in[5];
  const float* gw = (const float*)d_in[6];

  char* base = (char*)d_ws;
  uint16_t* xb   = (uint16_t*)(base);                       // [0,32)
  uint16_t* U    = (uint16_t*)(base);                       // overlays xb (scan)
  uint16_t* qkb  = (uint16_t*)(base + ((size_t)32 << 20));  // [32,64)
  uint16_t* vb   = (uint16_t*)(base + ((size_t)64 << 20));  // [64,96)
  uint16_t* kt   = (uint16_t*)(base + ((size_t)64 << 20));  // overlays vb
  uint16_t* attn = (uint16_t*)(base + ((size_t)80 << 20));  // overlays vb
  uint16_t* wob  = (uint16_t*)(base + ((size_t)84 << 20));  // overlays vb
  uint16_t* gb   = (uint16_t*)(base + ((size_t)96 << 20));  // [96,128)
  uint16_t* wqkb = (uint16_t*)(base + ((size_t)128 << 20)); // [128,136)
  uint16_t* wvb  = (uint16_t*)(base + ((size_t)136 << 20)); // [136,144)
  uint16_t* wgb  = (uint16_t*)(base + ((size_t)144 << 20)); // [144,152)
  uint16_t* vt   = (uint16_t*)(base + ((size_t)128 << 20)); // overlays weights
  uint16_t* qb   = qkb;                    // q = cols 0-1023
  uint16_t* o16  = (uint16_t*)d_out;       // bf16 o scratch (first 32MB)

  dim3 blk(256), blkG(512);
  // phase 1: conversions + the four big GEMMs (xb read by qk, v, g)
  conv_f2b<<<dim3(8192), blk, 0, stream>>>(x,  xb,  M * DM / 8);
  conv_f2b<<<dim3(1024), blk, 0, stream>>>(Wq, wqkb, 1024 * DM / 8);
  conv_f2b<<<dim3(1024), blk, 0, stream>>>(Wk, wqkb + 1024 * DM, 1024 * DM / 8);
  conv_f2b<<<dim3(2048), blk, 0, stream>>>(Wv, wvb, DM * DM / 8);
  conv_f2b<<<dim3(2048), blk, 0, stream>>>(Wg, wgb, DM * DM / 8);
  gemm256<true><<<dim3(M/256, DM/256), blkG, 0, stream>>>(xb, wqkb, qkb, DM, DM);
  gemm256<true><<<dim3(M/256, DM/256), blkG, 0, stream>>>(xb, wvb,  vb,  DM, DM);
  gemm256<true><<<dim3(M/256, DM/256), blkG, 0, stream>>>(xb, wgb,  gb,  DM, DM);
  // phase 2: rope; global transposes (vb dies, weights die); attn
  rope_kernel<<<dim3((Bb*Nn*Hh*128)/256), blk, 0, stream>>>(qkb);
  transpose_v<<<dim3(8*8*64), blk, 0, stream>>>(vb, vt);     // vb -> dead
  conv_f2b<<<dim3(2048), blk, 0, stream>>>(Wo, wob, DM * DM / 8);
  transpose_k<<<dim3(8*4*64), blk, 0, stream>>>(qkb, kt);
  attn_mfma<<<dim3(Bb*Hh*NC), blk, 0, stream>>>(qkb, attn);
  // scan: 4 passes of 128 dv cols; U overlays dead xb
  for (int p = 0; p < 4; ++p) {
    chunk_outer<<<dim3(Bb*Hh*NC),  blk, 0, stream>>>(kt, vt, U, p);
    state_scan<<<dim3(1024),       blk, 0, stream>>>(U);
    scan_out<<<dim3(Bb*Hh*NC),     blk, 0, stream>>>(qb, vt, attn, U, o16, p);
  }
  // epilogue
  gn_gate<<<dim3(M), blk, 0, stream>>>(o16, gb, gw);
  gemm256<false><<<dim3(M/256, DM/256), blkG, 0, stream>>>(gb, wob, (float*)d_out, DM, DM);
}